// Round 22
// baseline (139.186 us; speedup 1.0000x reference)
//
#include <hip/hip_runtime.h>
#include <hip/hip_bf16.h>
#include <hip/hip_fp16.h>
#include <cstddef>

#define N_NODES 50000
#define IN_DIM 256
#define HID_DIM 64
#define OUT_DIM 40
#define N_EDGES 800000
#define NBLK 196            // ceil(N_NODES / 256)
#define GEMM1_BLOCKS 782    // ceil(N_NODES / 64)
#define CNT_BLOCKS 3125     // 1 edge/thread
#define FILL_BLOCKS 3125
#define SCALE_BLOCKS 1563   // ceil(N_NODES*64/8 / 256)
#define CNT_STRIDE 32       // 128 B per node: 1 node per L2 line (R21 was 4)
#define INIT_BLOCKS 6250    // ceil(N_NODES*CNT_STRIDE / 256)

typedef _Float16 f16x8 __attribute__((ext_vector_type(8)));
typedef float f32x4 __attribute__((ext_vector_type(4)));

// ---------------------------------------------------------------------------
// K0: zero padded histogram + build W1^T in fp16 (w1t[c][k] = W1[k][c])
__global__ void k_init(int* __restrict__ cnt, const float* __restrict__ W1,
                       __half* __restrict__ w1t) {
    int i = blockIdx.x * 256 + threadIdx.x;
    if (i < N_NODES * CNT_STRIDE) cnt[i] = 0;
    if (i < IN_DIM * HID_DIM) {
        int c = i >> 8, k = i & 255;
        w1t[i] = __float2half(W1[(size_t)k * HID_DIM + c]);
    }
}

// K1: FUSED gemm1 (UNSCALED h1) + degree-count.
// Count atomics hit cnt[d*CNT_STRIDE] -- one L2 line per node.
__global__ __launch_bounds__(256) void k_gemm1_count(
        const float* __restrict__ x, const __half* __restrict__ w1t,
        __half* __restrict__ h1,
        const int* __restrict__ dst, int* __restrict__ cnt,
        unsigned short* __restrict__ rank_) {
    __shared__ _Float16 xh[64][72];   // 18 KB total (R20-proven occupancy)
    __shared__ _Float16 wt[64][72];
    const int tid = threadIdx.x;
    if (blockIdx.x >= GEMM1_BLOCKS) {            // ---- count path ----
        int i = (blockIdx.x - GEMM1_BLOCKS) * 256 + tid;
        if (i < N_EDGES)
            rank_[i] = (unsigned short)atomicAdd(&cnt[dst[i] * CNT_STRIDE], 1);
        return;
    }
    // ---- gemm1 path (four K=64 phases, 18 KB LDS) ----
    const int row0 = blockIdx.x * 64;
    const int r = tid >> 2, q = tid & 3;
    const int wv = tid >> 6, l = tid & 63;
    const int rowa = wv * 16 + (l & 15);
    const int koff = (l >> 4) * 8;
    const int grow_s = row0 + r;
    f32x4 acc0 = {0.f, 0.f, 0.f, 0.f}, acc1 = acc0, acc2 = acc0, acc3 = acc0;
#pragma unroll
    for (int kh = 0; kh < 4; ++kh) {
        __syncthreads();                         // prev phase fully consumed
        {
            const uint4* wsrc = (const uint4*)(w1t + (size_t)r * 256 + kh * 64 + q * 16);
            uint4* wdst = (uint4*)&wt[r][q * 16];
            wdst[0] = wsrc[0];
            wdst[1] = wsrc[1];
            const float4* xsrc = (const float4*)(x + (size_t)grow_s * IN_DIM + kh * 64 + q * 16);
#pragma unroll
            for (int i = 0; i < 2; ++i) {
                float4 f0 = make_float4(0.f, 0.f, 0.f, 0.f), f1 = f0;
                if (grow_s < N_NODES) { f0 = xsrc[2 * i]; f1 = xsrc[2 * i + 1]; }
                f16x8 v;
                v[0] = (_Float16)f0.x; v[1] = (_Float16)f0.y;
                v[2] = (_Float16)f0.z; v[3] = (_Float16)f0.w;
                v[4] = (_Float16)f1.x; v[5] = (_Float16)f1.y;
                v[6] = (_Float16)f1.z; v[7] = (_Float16)f1.w;
                *(f16x8*)&xh[r][q * 16 + i * 8] = v;
            }
        }
        __syncthreads();
#pragma unroll
        for (int ks = 0; ks < 2; ++ks) {
            f16x8 a  = *(const f16x8*)&xh[rowa][ks * 32 + koff];
            f16x8 b0 = *(const f16x8*)&wt[ 0 + (l & 15)][ks * 32 + koff];
            f16x8 b1 = *(const f16x8*)&wt[16 + (l & 15)][ks * 32 + koff];
            f16x8 b2 = *(const f16x8*)&wt[32 + (l & 15)][ks * 32 + koff];
            f16x8 b3 = *(const f16x8*)&wt[48 + (l & 15)][ks * 32 + koff];
            acc0 = __builtin_amdgcn_mfma_f32_16x16x32_f16(a, b0, acc0, 0, 0, 0);
            acc1 = __builtin_amdgcn_mfma_f32_16x16x32_f16(a, b1, acc1, 0, 0, 0);
            acc2 = __builtin_amdgcn_mfma_f32_16x16x32_f16(a, b2, acc2, 0, 0, 0);
            acc3 = __builtin_amdgcn_mfma_f32_16x16x32_f16(a, b3, acc3, 0, 0, 0);
        }
    }
    // C/D: col = lane&15, row = (lane>>4)*4 + reg  [m89-verified]
    const int colc = l & 15;
#pragma unroll
    for (int rr = 0; rr < 4; ++rr) {
        int grow = row0 + wv * 16 + (l >> 4) * 4 + rr;
        if (grow < N_NODES) {
            __half* dst2 = h1 + (size_t)grow * HID_DIM;
            dst2[ 0 + colc] = __float2half(acc0[rr]);
            dst2[16 + colc] = __float2half(acc1[rr]);
            dst2[32 + colc] = __float2half(acc2[rr]);
            dst2[48 + colc] = __float2half(acc3[rr]);
        }
    }
}

// K2a: per-block exclusive scan of cnt (strided) -> rowptr + block sums
__global__ void k_scan1(const int* __restrict__ cnt, int* __restrict__ excl,
                        int* __restrict__ bsum) {
    __shared__ int wsum[4];
    int i = blockIdx.x * 256 + threadIdx.x;
    int lane = threadIdx.x & 63, w = threadIdx.x >> 6;
    int v = (i < N_NODES) ? cnt[(size_t)i * CNT_STRIDE] : 0;
    int inc = v;
    for (int o = 1; o < 64; o <<= 1) {
        int t = __shfl_up(inc, o);
        if (lane >= o) inc += t;
    }
    if (lane == 63) wsum[w] = inc;
    __syncthreads();
    int off = 0;
    for (int k = 0; k < w; ++k) off += wsum[k];
    if (i < N_NODES) excl[i] = off + inc - v;
    if (threadIdx.x == 255) bsum[blockIdx.x] = off + inc;
}

// K2b: MERGED scan2+scan3: every block redundantly scans the 196 block sums,
// applies its own offset, computes dinv (cnt strided).
__global__ void k_scan23(int* __restrict__ rowptr, const int* __restrict__ bsum,
                         const int* __restrict__ cnt, float* __restrict__ dinv) {
    __shared__ int wsum[4];
    __shared__ int myoff;
    int t = threadIdx.x;
    int lane = t & 63, w = t >> 6;
    int v = (t < NBLK) ? bsum[t] : 0;
    int inc = v;
    for (int o = 1; o < 64; o <<= 1) {
        int u = __shfl_up(inc, o);
        if (lane >= o) inc += u;
    }
    if (lane == 63) wsum[w] = inc;
    __syncthreads();
    int off = 0;
    for (int k = 0; k < w; ++k) off += wsum[k];
    if (t == blockIdx.x) myoff = off + inc - v;
    __syncthreads();
    int i = blockIdx.x * 256 + t;
    if (i < N_NODES) {
        rowptr[i] += myoff;
        dinv[i] = rsqrtf((float)cnt[(size_t)i * CNT_STRIDE] + 1.0f);
    } else if (i == N_NODES) {
        rowptr[i] = N_EDGES;
    }
}

// K3: FUSED fill + g1-scale. Blocks [0, FILL_BLOCKS) = atomic-free CSR fill;
// blocks [FILL_BLOCKS, +SCALE_BLOCKS) = g1[row][*] *= dinv[row] (in place).
__global__ void k_fill_scale(const int* __restrict__ src, const int* __restrict__ dst,
                             const int* __restrict__ rowptr,
                             const unsigned short* __restrict__ rank_,
                             unsigned short* __restrict__ esrc,
                             __half* __restrict__ g1, const float* __restrict__ dinv) {
    if (blockIdx.x < FILL_BLOCKS) {
        int i = blockIdx.x * 256 + threadIdx.x;
        if (i < N_EDGES) {
            int d = dst[i];
            esrc[rowptr[d] + rank_[i]] = (unsigned short)src[i];
        }
        return;
    }
    int idx = (blockIdx.x - FILL_BLOCKS) * 256 + threadIdx.x;   // uint4 index
    if (idx >= N_NODES * HID_DIM / 8) return;
    int row = idx >> 3;
    float dv = dinv[row];
    uint4 v = *(uint4*)&g1[(size_t)idx * 8];
    union { __half2 h2v[4]; uint4 u; } pk;
    const __half2* hv = (const __half2*)&v;
#pragma unroll
    for (int i = 0; i < 4; ++i) {
        float2 f = __half22float2(hv[i]);
        pk.h2v[i] = __floats2half2_rn(f.x * dv, f.y * dv);
    }
    *(uint4*)&g1[(size_t)idx * 8] = pk.u;
}

// K4: gather aggregation DIM=64 (pre-scaled fp16 in), fused bias+ReLU,
// fp16 output. uint4 structure: 8 parities x 8 lanes x 16B.
__global__ __launch_bounds__(256) void k_agg_relu(const int* __restrict__ rowptr,
        const unsigned short* __restrict__ esrc, const float* __restrict__ dinv,
        const uint4* __restrict__ g,        // [N][8] uint4 (=64 half)
        const float* __restrict__ b,
        __half* __restrict__ out) {         // agg1 [N][64] fp16
    int wid  = (int)((blockIdx.x * (size_t)blockDim.x + threadIdx.x) >> 6);
    int lane = threadIdx.x & 63;
    if (wid >= N_NODES) return;
    int p = lane >> 3;        // edge parity 0..7
    int c = lane & 7;         // uint4 channel group (8 halves)
    float a0 = 0.f, a1 = 0.f, a2 = 0.f, a3 = 0.f;
    float a4 = 0.f, a5 = 0.f, a6 = 0.f, a7 = 0.f;
#define ACC_U4(v)  do {                                            \
        float2 f0 = __half22float2(*(const __half2*)&(v).x);       \
        float2 f1 = __half22float2(*(const __half2*)&(v).y);       \
        float2 f2 = __half22float2(*(const __half2*)&(v).z);       \
        float2 f3 = __half22float2(*(const __half2*)&(v).w);       \
        a0 += f0.x; a1 += f0.y; a2 += f1.x; a3 += f1.y;            \
        a4 += f2.x; a5 += f2.y; a6 += f3.x; a7 += f3.y; } while (0)
    if (p == 0) { uint4 v = g[(size_t)wid * 8 + c]; ACC_U4(v); }   // self-loop
    int beg = rowptr[wid], deg = rowptr[wid + 1] - beg;
    for (int base = 0; base < deg; base += 64) {          // uniform
        int nb = deg - base; if (nb > 64) nb = 64;        // uniform
        int idx = (lane < nb) ? (int)esrc[beg + base + lane] : 0;  // coalesced
        for (int eb = 0; eb < nb; eb += 32) {             // uniform bound
            int e0 = eb + p;                              // e0+24 <= 63 always
            int s0 = __shfl(idx, e0);
            int s1 = __shfl(idx, e0 + 8);
            int s2 = __shfl(idx, e0 + 16);
            int s3 = __shfl(idx, e0 + 24);
            if (e0 + 24 < nb) {                           // fast path: all 4
                uint4 v0 = g[(size_t)s0 * 8 + c];
                uint4 v1 = g[(size_t)s1 * 8 + c];
                uint4 v2 = g[(size_t)s2 * 8 + c];
                uint4 v3 = g[(size_t)s3 * 8 + c];
                ACC_U4(v0); ACC_U4(v1); ACC_U4(v2); ACC_U4(v3);
            } else {                                      // tail: per-edge guard
                if (e0      < nb) { uint4 v = g[(size_t)s0 * 8 + c]; ACC_U4(v); }
                if (e0 + 8  < nb) { uint4 v = g[(size_t)s1 * 8 + c]; ACC_U4(v); }
                if (e0 + 16 < nb) { uint4 v = g[(size_t)s2 * 8 + c]; ACC_U4(v); }
            }
        }
    }
#undef ACC_U4
    a0 += __shfl_xor(a0, 8); a0 += __shfl_xor(a0, 16); a0 += __shfl_xor(a0, 32);
    a1 += __shfl_xor(a1, 8); a1 += __shfl_xor(a1, 16); a1 += __shfl_xor(a1, 32);
    a2 += __shfl_xor(a2, 8); a2 += __shfl_xor(a2, 16); a2 += __shfl_xor(a2, 32);
    a3 += __shfl_xor(a3, 8); a3 += __shfl_xor(a3, 16); a3 += __shfl_xor(a3, 32);
    a4 += __shfl_xor(a4, 8); a4 += __shfl_xor(a4, 16); a4 += __shfl_xor(a4, 32);
    a5 += __shfl_xor(a5, 8); a5 += __shfl_xor(a5, 16); a5 += __shfl_xor(a5, 32);
    a6 += __shfl_xor(a6, 8); a6 += __shfl_xor(a6, 16); a6 += __shfl_xor(a6, 32);
    a7 += __shfl_xor(a7, 8); a7 += __shfl_xor(a7, 16); a7 += __shfl_xor(a7, 32);
    if (lane < 8) {
        float dd = dinv[wid];
        float4 b0v = *(const float4*)&b[c * 8 + 0];
        float4 b1v = *(const float4*)&b[c * 8 + 4];
        union { __half2 h2v[4]; uint4 u; } pk;
        pk.h2v[0] = __floats2half2_rn(fmaxf(a0 * dd + b0v.x, 0.f),
                                      fmaxf(a1 * dd + b0v.y, 0.f));
        pk.h2v[1] = __floats2half2_rn(fmaxf(a2 * dd + b0v.z, 0.f),
                                      fmaxf(a3 * dd + b0v.w, 0.f));
        pk.h2v[2] = __floats2half2_rn(fmaxf(a4 * dd + b1v.x, 0.f),
                                      fmaxf(a5 * dd + b1v.y, 0.f));
        pk.h2v[3] = __floats2half2_rn(fmaxf(a6 * dd + b1v.z, 0.f),
                                      fmaxf(a7 * dd + b1v.w, 0.f));
        *(uint4*)&out[(size_t)wid * HID_DIM + c * 8] = pk.u;
    }
}

// K5: g2 = dinv * (a @ W2)  [50000,64]x[64,40]; fp16 in, fp16 out [N][40]
__global__ void k_gemm2(const __half* __restrict__ a, const float* __restrict__ W2,
                        const float* __restrict__ dinv, __half* __restrict__ g2) {
    int idx = blockIdx.x * blockDim.x + threadIdx.x;
    if (idx >= N_NODES * (OUT_DIM / 4)) return;
    int row = idx / (OUT_DIM / 4);
    int cg  = idx - row * (OUT_DIM / 4);
    const uint2* ar = (const uint2*)(a + (size_t)row * HID_DIM);
    float4 acc = make_float4(0.f, 0.f, 0.f, 0.f);
#pragma unroll
    for (int kk = 0; kk < 16; ++kk) {
        uint2 hv = ar[kk];
        float2 f0 = __half22float2(*(const __half2*)&hv.x);
        float2 f1 = __half22float2(*(const __half2*)&hv.y);
        float4 w0 = *(const float4*)&W2[(kk * 4 + 0) * OUT_DIM + cg * 4];
        float4 w1 = *(const float4*)&W2[(kk * 4 + 1) * OUT_DIM + cg * 4];
        float4 w2 = *(const float4*)&W2[(kk * 4 + 2) * OUT_DIM + cg * 4];
        float4 w3 = *(const float4*)&W2[(kk * 4 + 3) * OUT_DIM + cg * 4];
        acc.x += f0.x * w0.x + f0.y * w1.x + f1.x * w2.x + f1.y * w3.x;
        acc.y += f0.x * w0.y + f0.y * w1.y + f1.x * w2.y + f1.y * w3.y;
        acc.z += f0.x * w0.z + f0.y * w1.z + f1.x * w2.z + f1.y * w3.z;
        acc.w += f0.x * w0.w + f0.y * w1.w + f1.x * w2.w + f1.y * w3.w;
    }
    float dv = dinv[row];
    union { __half2 h2v[2]; uint2 u; } pk;
    pk.h2v[0] = __floats2half2_rn(acc.x * dv, acc.y * dv);
    pk.h2v[1] = __floats2half2_rn(acc.z * dv, acc.w * dv);
    *(uint2*)&g2[(size_t)row * OUT_DIM + cg * 4] = pk.u;
}

// K6: layer-2 aggregation (pre-scaled fp16 in), fused bias + log_softmax.
__global__ __launch_bounds__(256) void k_agg_lsm(const int* __restrict__ rowptr,
        const unsigned short* __restrict__ esrc, const float* __restrict__ dinv,
        const uint2* __restrict__ g,        // [N][10] uint2 (=40 half)
        const float* __restrict__ b,
        float* __restrict__ out) {
    int wid  = (int)((blockIdx.x * (size_t)blockDim.x + threadIdx.x) >> 6);
    int lane = threadIdx.x & 63;
    if (wid >= N_NODES) return;
    int p = lane >> 4;
    int c = lane & 15;
    bool act = (c < 10);
    float ax = 0.f, ay = 0.f, az = 0.f, aw = 0.f;
#define ACC_U2(v)  do {                                            \
        float2 f0 = __half22float2(*(const __half2*)&(v).x);       \
        float2 f1 = __half22float2(*(const __half2*)&(v).y);       \
        ax += f0.x; ay += f0.y; az += f1.x; aw += f1.y; } while (0)
    if (p == 0 && act) { uint2 v = g[(size_t)wid * 10 + c]; ACC_U2(v); }
    int beg = rowptr[wid], deg = rowptr[wid + 1] - beg;
    for (int base = 0; base < deg; base += 64) {          // uniform
        int nb = deg - base; if (nb > 64) nb = 64;        // uniform
        int idx = (lane < nb) ? (int)esrc[beg + base + lane] : 0;
        for (int eb = 0; eb < nb; eb += 16) {             // uniform bound
            int e0 = eb + p;
            int s0 = __shfl(idx, e0);
            int s1 = __shfl(idx, e0 + 4);
            int s2 = __shfl(idx, e0 + 8);
            int s3 = __shfl(idx, e0 + 12);
            if (act) {
                if (e0 + 12 < nb) {
                    uint2 v0 = g[(size_t)s0 * 10 + c];
                    uint2 v1 = g[(size_t)s1 * 10 + c];
                    uint2 v2 = g[(size_t)s2 * 10 + c];
                    uint2 v3 = g[(size_t)s3 * 10 + c];
                    ACC_U2(v0); ACC_U2(v1); ACC_U2(v2); ACC_U2(v3);
                } else {
                    if (e0      < nb) { uint2 v = g[(size_t)s0 * 10 + c]; ACC_U2(v); }
                    if (e0 + 4  < nb) { uint2 v = g[(size_t)s1 * 10 + c]; ACC_U2(v); }
                    if (e0 + 8  < nb) { uint2 v = g[(size_t)s2 * 10 + c]; ACC_U2(v); }
                }
            }
        }
    }
#undef ACC_U2
    ax += __shfl_xor(ax, 16); ax += __shfl_xor(ax, 32);
    ay += __shfl_xor(ay, 16); ay += __shfl_xor(ay, 32);
    az += __shfl_xor(az, 16); az += __shfl_xor(az, 32);
    aw += __shfl_xor(aw, 16); aw += __shfl_xor(aw, 32);
    float dd = dinv[wid];
    float vx = -INFINITY, vy = -INFINITY, vz = -INFINITY, vw = -INFINITY;
    if (act) {
        float4 bb = *(const float4*)&b[c * 4];
        vx = ax * dd + bb.x; vy = ay * dd + bb.y;
        vz = az * dd + bb.z; vw = aw * dd + bb.w;
    }
    float m = fmaxf(fmaxf(vx, vy), fmaxf(vz, vw));
    for (int o = 8; o; o >>= 1) m = fmaxf(m, __shfl_xor(m, o));
    float es = act ? (__expf(vx - m) + __expf(vy - m) + __expf(vz - m) + __expf(vw - m)) : 0.f;
    for (int o = 8; o; o >>= 1) es += __shfl_xor(es, o);
    float ls = __logf(es);
    if (lane < 16 && act) {
        float4 o4 = make_float4(vx - m - ls, vy - m - ls, vz - m - ls, vw - m - ls);
        *(float4*)&out[(size_t)wid * OUT_DIM + c * 4] = o4;
    }
}

extern "C" void kernel_launch(void* const* d_in, const int* in_sizes, int n_in,
                              void* d_out, int out_size, void* d_ws, size_t ws_size,
                              hipStream_t stream) {
    const float* x    = (const float*)d_in[0];
    const int*   ei   = (const int*)d_in[1];
    const int*   srcp = ei;             // edge_index[0]
    const int*   dstp = ei + N_EDGES;   // edge_index[1]
    const float* W1   = (const float*)d_in[2];
    const float* b1   = (const float*)d_in[3];
    const float* W2   = (const float*)d_in[4];
    const float* b2   = (const float*)d_in[5];
    float* out = (float*)d_out;

    // workspace layout (~27 MB)
    char* p = (char*)d_ws;
    int*            cnt    = (int*)p;            p += (size_t)N_NODES * CNT_STRIDE * 4;
    int*            rowptr = (int*)p;            p += (size_t)(N_NODES + 4) * 4;
    unsigned short* rank_  = (unsigned short*)p; p += (size_t)N_EDGES * 2;
    unsigned short* esrc   = (unsigned short*)p; p += (size_t)N_EDGES * 2;
    int*            bsum   = (int*)p;            p += 256 * 4;
    float*          dinv   = (float*)p;          p += (size_t)N_NODES * 4;
    __half*         w1t    = (__half*)p;         p += (size_t)IN_DIM * HID_DIM * 2;
    __half*         g1     = (__half*)p;         p += (size_t)N_NODES * HID_DIM * 2;
    __half*         agg1   = (__half*)p;         p += (size_t)N_NODES * HID_DIM * 2;
    __half*         g2     = (__half*)p;         p += (size_t)N_NODES * OUT_DIM * 2;

    k_init<<<INIT_BLOCKS, 256, 0, stream>>>(cnt, W1, w1t);

    k_gemm1_count<<<GEMM1_BLOCKS + CNT_BLOCKS, 256, 0, stream>>>(
        x, w1t, g1, dstp, cnt, rank_);

    k_scan1<<<NBLK, 256, 0, stream>>>(cnt, rowptr, bsum);
    k_scan23<<<NBLK, 256, 0, stream>>>(rowptr, bsum, cnt, dinv);

    k_fill_scale<<<FILL_BLOCKS + SCALE_BLOCKS, 256, 0, stream>>>(
        srcp, dstp, rowptr, rank_, esrc, g1, dinv);

    k_agg_relu<<<(N_NODES + 3) / 4, 256, 0, stream>>>(rowptr, esrc, dinv,
                                                      (const uint4*)g1, b1, agg1);

    k_gemm2<<<(N_NODES * (OUT_DIM / 4) + 255) / 256, 256, 0, stream>>>(agg1, W2, dinv, g2);

    k_agg_lsm<<<(N_NODES + 3) / 4, 256, 0, stream>>>(rowptr, esrc, dinv,
                                                     (const uint2*)g2, b2, out);
}

// Round 23
// 136.121 us; speedup vs baseline: 1.0225x; 1.0225x over previous
//
#include <hip/hip_runtime.h>
#include <hip/hip_bf16.h>
#include <hip/hip_fp16.h>
#include <cstddef>

#define N_NODES 50000
#define IN_DIM 256
#define HID_DIM 64
#define OUT_DIM 40
#define N_EDGES 800000
#define NBINS 196           // ceil(N_NODES / 256); bin(d) = d >> 8
#define GEMM1_BLOCKS 782    // ceil(N_NODES / 64)
#define EH_BLOCKS 3125      // ceil(N_EDGES / 256)

typedef _Float16 f16x8 __attribute__((ext_vector_type(8)));
typedef float f32x4 __attribute__((ext_vector_type(4)));

// ---------------------------------------------------------------------------
// K0: build W1^T in fp16 (w1t[c][k] = W1[k][c]); no histogram zeroing needed.
__global__ void k_init(const float* __restrict__ W1, __half* __restrict__ w1t) {
    int i = blockIdx.x * 256 + threadIdx.x;
    if (i < IN_DIM * HID_DIM) {
        int c = i >> 8, k = i & 255;
        w1t[i] = __float2half(W1[(size_t)k * HID_DIM + c]);
    }
}

// K1: FUSED gemm1 (UNSCALED h1 -> g1) + per-block coarse histogram (dst>>8).
// hist path uses ONLY LDS atomics; writes hist[hb*NBINS + bin] coalesced.
__global__ __launch_bounds__(256) void k_gemm1_hist(
        const float* __restrict__ x, const __half* __restrict__ w1t,
        __half* __restrict__ g1,
        const int* __restrict__ dst, int* __restrict__ hist) {
    __shared__ _Float16 xh[64][72];   // 18 KB total; hist path aliases into xh
    __shared__ _Float16 wt[64][72];
    const int tid = threadIdx.x;
    if (blockIdx.x >= GEMM1_BLOCKS) {            // ---- hist path ----
        int* lh = (int*)&xh[0][0];               // 196 ints
        if (tid < NBINS) lh[tid] = 0;
        __syncthreads();
        int i = (blockIdx.x - GEMM1_BLOCKS) * 256 + tid;
        if (i < N_EDGES) atomicAdd(&lh[dst[i] >> 8], 1);   // LDS atomic
        __syncthreads();
        if (tid < NBINS)
            hist[(size_t)(blockIdx.x - GEMM1_BLOCKS) * NBINS + tid] = lh[tid];
        return;
    }
    // ---- gemm1 path (four K=64 phases, 18 KB LDS) ----
    const int row0 = blockIdx.x * 64;
    const int r = tid >> 2, q = tid & 3;
    const int wv = tid >> 6, l = tid & 63;
    const int rowa = wv * 16 + (l & 15);
    const int koff = (l >> 4) * 8;
    const int grow_s = row0 + r;
    f32x4 acc0 = {0.f, 0.f, 0.f, 0.f}, acc1 = acc0, acc2 = acc0, acc3 = acc0;
#pragma unroll
    for (int kh = 0; kh < 4; ++kh) {
        __syncthreads();
        {
            const uint4* wsrc = (const uint4*)(w1t + (size_t)r * 256 + kh * 64 + q * 16);
            uint4* wdst = (uint4*)&wt[r][q * 16];
            wdst[0] = wsrc[0];
            wdst[1] = wsrc[1];
            const float4* xsrc = (const float4*)(x + (size_t)grow_s * IN_DIM + kh * 64 + q * 16);
#pragma unroll
            for (int i = 0; i < 2; ++i) {
                float4 f0 = make_float4(0.f, 0.f, 0.f, 0.f), f1 = f0;
                if (grow_s < N_NODES) { f0 = xsrc[2 * i]; f1 = xsrc[2 * i + 1]; }
                f16x8 v;
                v[0] = (_Float16)f0.x; v[1] = (_Float16)f0.y;
                v[2] = (_Float16)f0.z; v[3] = (_Float16)f0.w;
                v[4] = (_Float16)f1.x; v[5] = (_Float16)f1.y;
                v[6] = (_Float16)f1.z; v[7] = (_Float16)f1.w;
                *(f16x8*)&xh[r][q * 16 + i * 8] = v;
            }
        }
        __syncthreads();
#pragma unroll
        for (int ks = 0; ks < 2; ++ks) {
            f16x8 a  = *(const f16x8*)&xh[rowa][ks * 32 + koff];
            f16x8 b0 = *(const f16x8*)&wt[ 0 + (l & 15)][ks * 32 + koff];
            f16x8 b1 = *(const f16x8*)&wt[16 + (l & 15)][ks * 32 + koff];
            f16x8 b2 = *(const f16x8*)&wt[32 + (l & 15)][ks * 32 + koff];
            f16x8 b3 = *(const f16x8*)&wt[48 + (l & 15)][ks * 32 + koff];
            acc0 = __builtin_amdgcn_mfma_f32_16x16x32_f16(a, b0, acc0, 0, 0, 0);
            acc1 = __builtin_amdgcn_mfma_f32_16x16x32_f16(a, b1, acc1, 0, 0, 0);
            acc2 = __builtin_amdgcn_mfma_f32_16x16x32_f16(a, b2, acc2, 0, 0, 0);
            acc3 = __builtin_amdgcn_mfma_f32_16x16x32_f16(a, b3, acc3, 0, 0, 0);
        }
    }
    // C/D: col = lane&15, row = (lane>>4)*4 + reg  [m89-verified]
    const int colc = l & 15;
#pragma unroll
    for (int rr = 0; rr < 4; ++rr) {
        int grow = row0 + wv * 16 + (l >> 4) * 4 + rr;
        if (grow < N_NODES) {
            __half* dst2 = g1 + (size_t)grow * HID_DIM;
            dst2[ 0 + colc] = __float2half(acc0[rr]);
            dst2[16 + colc] = __float2half(acc1[rr]);
            dst2[32 + colc] = __float2half(acc2[rr]);
            dst2[48 + colc] = __float2half(acc3[rr]);
        }
    }
}

// K2: per-bin column scan. Block b converts hist[:, b] to its exclusive
// prefix (in place) and writes total[b]. CH = 13 rows per thread (13*256>=3125).
__global__ __launch_bounds__(256) void k_scanbins(int* __restrict__ hist,
                                                  int* __restrict__ total) {
    __shared__ int wsum[4];
    const int b = blockIdx.x, t = threadIdx.x;
    const int lane = t & 63, w = t >> 6;
    int vals[13];
    int lsum = 0;
#pragma unroll
    for (int i = 0; i < 13; ++i) {
        int j = t * 13 + i;
        vals[i] = (j < EH_BLOCKS) ? hist[(size_t)j * NBINS + b] : 0;
        lsum += vals[i];
    }
    int inc = lsum;
#pragma unroll
    for (int o = 1; o < 64; o <<= 1) {
        int u = __shfl_up(inc, o);
        if (lane >= o) inc += u;
    }
    if (lane == 63) wsum[w] = inc;
    __syncthreads();
    int off = 0;
    for (int k = 0; k < w; ++k) off += wsum[k];
    int run = off + inc - lsum;          // exclusive prefix of this chunk
#pragma unroll
    for (int i = 0; i < 13; ++i) {
        int j = t * 13 + i;
        if (j < EH_BLOCKS) hist[(size_t)j * NBINS + b] = run;
        run += vals[i];
    }
    if (t == 255) total[b] = run;
}

// K3: scatter edges into bucket-grouped packed array (LDS atomics only).
// packed = dst<<16 | src (both < 65536).
__global__ __launch_bounds__(256) void k_scatter1(
        const int* __restrict__ src, const int* __restrict__ dst,
        const int* __restrict__ hist, const int* __restrict__ total,
        unsigned int* __restrict__ packed) {
    __shared__ int wsum[4];
    __shared__ int cursor[NBINS];
    const int t = threadIdx.x;
    const int lane = t & 63, w = t >> 6;
    // redundant exclusive scan of total[196] -> binstart
    int v = (t < NBINS) ? total[t] : 0;
    int inc = v;
#pragma unroll
    for (int o = 1; o < 64; o <<= 1) {
        int u = __shfl_up(inc, o);
        if (lane >= o) inc += u;
    }
    if (lane == 63) wsum[w] = inc;
    __syncthreads();
    int off = 0;
    for (int k = 0; k < w; ++k) off += wsum[k];
    int excl = off + inc - v;
    if (t < NBINS)
        cursor[t] = excl + hist[(size_t)blockIdx.x * NBINS + t];
    __syncthreads();
    int i = blockIdx.x * 256 + t;
    if (i < N_EDGES) {
        int d = dst[i], s = src[i];
        int pos = atomicAdd(&cursor[d >> 8], 1);          // LDS atomic
        packed[pos] = ((unsigned)d << 16) | (unsigned)s;
    }
}

// K4: per-bin CSR build + g1 scale. Block b: pass A counts per-node degree
// (LDS), block scan -> rowptr/dinv; pass B scatters esrc via LDS cursors;
// then scales its 256 g1 rows with LDS-resident dinv.
__global__ __launch_bounds__(256) void k_build(
        const unsigned int* __restrict__ packed, const int* __restrict__ total,
        int* __restrict__ rowptr, float* __restrict__ dinv,
        unsigned short* __restrict__ esrc, __half* __restrict__ g1) {
    __shared__ int wsum[4];
    __shared__ int degl[256];
    __shared__ int curl[256];
    __shared__ float dinvl[256];
    __shared__ int bs2[2];
    const int b = blockIdx.x, t = threadIdx.x;
    const int lane = t & 63, w = t >> 6;
    // redundant exclusive scan of total -> need entries b and b+1
    {
        int v = (t < NBINS) ? total[t] : 0;
        int inc = v;
#pragma unroll
        for (int o = 1; o < 64; o <<= 1) {
            int u = __shfl_up(inc, o);
            if (lane >= o) inc += u;
        }
        if (lane == 63) wsum[w] = inc;
        __syncthreads();
        int off = 0;
        for (int k = 0; k < w; ++k) off += wsum[k];
        int excl = off + inc - v;
        if (t == b) bs2[0] = excl;
        if (t == b + 1) bs2[1] = excl;   // t=196 gives full sum = N_EDGES
        degl[t] = 0;
    }
    __syncthreads();
    const int s0 = bs2[0], s1 = bs2[1];
    // pass A: per-node degree count (LDS atomics)
    for (int e = s0 + t; e < s1; e += 256)
        atomicAdd(&degl[(packed[e] >> 16) & 255], 1);
    __syncthreads();
    // block exclusive scan of degl
    int dv = degl[t];
    {
        int inc = dv;
#pragma unroll
        for (int o = 1; o < 64; o <<= 1) {
            int u = __shfl_up(inc, o);
            if (lane >= o) inc += u;
        }
        if (lane == 63) wsum[w] = inc;
        __syncthreads();
        int off = 0;
        for (int k = 0; k < w; ++k) off += wsum[k];
        int excl = off + inc - dv;
        int node = b * 256 + t;
        float di = rsqrtf((float)dv + 1.0f);
        if (node < N_NODES) {
            rowptr[node] = s0 + excl;
            dinv[node] = di;
        }
        if (node == N_NODES) rowptr[N_NODES] = N_EDGES;
        dinvl[t] = di;
        curl[t] = excl;
    }
    __syncthreads();
    // pass B: scatter src into CSR slots (LDS cursor atomics)
    for (int e = s0 + t; e < s1; e += 256) {
        unsigned pk = packed[e];
        int ln = (pk >> 16) & 255;
        int pos = s0 + atomicAdd(&curl[ln], 1);
        esrc[pos] = (unsigned short)(pk & 0xFFFFu);
    }
    // g1 scale for this bin's nodes (dinv from LDS, no global reads)
    for (int idx = t; idx < 256 * 8; idx += 256) {
        int ln = idx >> 3;
        int node = b * 256 + ln;
        if (node < N_NODES) {
            float di = dinvl[ln];
            uint4 v4 = *(uint4*)&g1[(size_t)node * HID_DIM + (idx & 7) * 8];
            union { __half2 h2v[4]; uint4 u; } pk2;
            const __half2* hv = (const __half2*)&v4;
#pragma unroll
            for (int i = 0; i < 4; ++i) {
                float2 f = __half22float2(hv[i]);
                pk2.h2v[i] = __floats2half2_rn(f.x * di, f.y * di);
            }
            *(uint4*)&g1[(size_t)node * HID_DIM + (idx & 7) * 8] = pk2.u;
        }
    }
}

// K5: gather aggregation DIM=64 (pre-scaled fp16 in), fused bias+ReLU,
// fp16 output. uint4 structure: 8 parities x 8 lanes x 16B.
__global__ __launch_bounds__(256) void k_agg_relu(const int* __restrict__ rowptr,
        const unsigned short* __restrict__ esrc, const float* __restrict__ dinv,
        const uint4* __restrict__ g,        // [N][8] uint4 (=64 half)
        const float* __restrict__ b,
        __half* __restrict__ out) {         // agg1 [N][64] fp16
    int wid  = (int)((blockIdx.x * (size_t)blockDim.x + threadIdx.x) >> 6);
    int lane = threadIdx.x & 63;
    if (wid >= N_NODES) return;
    int p = lane >> 3;        // edge parity 0..7
    int c = lane & 7;         // uint4 channel group (8 halves)
    float a0 = 0.f, a1 = 0.f, a2 = 0.f, a3 = 0.f;
    float a4 = 0.f, a5 = 0.f, a6 = 0.f, a7 = 0.f;
#define ACC_U4(v)  do {                                            \
        float2 f0 = __half22float2(*(const __half2*)&(v).x);       \
        float2 f1 = __half22float2(*(const __half2*)&(v).y);       \
        float2 f2 = __half22float2(*(const __half2*)&(v).z);       \
        float2 f3 = __half22float2(*(const __half2*)&(v).w);       \
        a0 += f0.x; a1 += f0.y; a2 += f1.x; a3 += f1.y;            \
        a4 += f2.x; a5 += f2.y; a6 += f3.x; a7 += f3.y; } while (0)
    if (p == 0) { uint4 v = g[(size_t)wid * 8 + c]; ACC_U4(v); }   // self-loop
    int beg = rowptr[wid], deg = rowptr[wid + 1] - beg;
    for (int base = 0; base < deg; base += 64) {          // uniform
        int nb = deg - base; if (nb > 64) nb = 64;        // uniform
        int idx = (lane < nb) ? (int)esrc[beg + base + lane] : 0;  // coalesced
        for (int eb = 0; eb < nb; eb += 32) {             // uniform bound
            int e0 = eb + p;                              // e0+24 <= 63 always
            int s0 = __shfl(idx, e0);
            int s1 = __shfl(idx, e0 + 8);
            int s2 = __shfl(idx, e0 + 16);
            int s3 = __shfl(idx, e0 + 24);
            if (e0 + 24 < nb) {                           // fast path: all 4
                uint4 v0 = g[(size_t)s0 * 8 + c];
                uint4 v1 = g[(size_t)s1 * 8 + c];
                uint4 v2 = g[(size_t)s2 * 8 + c];
                uint4 v3 = g[(size_t)s3 * 8 + c];
                ACC_U4(v0); ACC_U4(v1); ACC_U4(v2); ACC_U4(v3);
            } else {                                      // tail: per-edge guard
                if (e0      < nb) { uint4 v = g[(size_t)s0 * 8 + c]; ACC_U4(v); }
                if (e0 + 8  < nb) { uint4 v = g[(size_t)s1 * 8 + c]; ACC_U4(v); }
                if (e0 + 16 < nb) { uint4 v = g[(size_t)s2 * 8 + c]; ACC_U4(v); }
            }
        }
    }
#undef ACC_U4
    a0 += __shfl_xor(a0, 8); a0 += __shfl_xor(a0, 16); a0 += __shfl_xor(a0, 32);
    a1 += __shfl_xor(a1, 8); a1 += __shfl_xor(a1, 16); a1 += __shfl_xor(a1, 32);
    a2 += __shfl_xor(a2, 8); a2 += __shfl_xor(a2, 16); a2 += __shfl_xor(a2, 32);
    a3 += __shfl_xor(a3, 8); a3 += __shfl_xor(a3, 16); a3 += __shfl_xor(a3, 32);
    a4 += __shfl_xor(a4, 8); a4 += __shfl_xor(a4, 16); a4 += __shfl_xor(a4, 32);
    a5 += __shfl_xor(a5, 8); a5 += __shfl_xor(a5, 16); a5 += __shfl_xor(a5, 32);
    a6 += __shfl_xor(a6, 8); a6 += __shfl_xor(a6, 16); a6 += __shfl_xor(a6, 32);
    a7 += __shfl_xor(a7, 8); a7 += __shfl_xor(a7, 16); a7 += __shfl_xor(a7, 32);
    if (lane < 8) {
        float dd = dinv[wid];
        float4 b0v = *(const float4*)&b[c * 8 + 0];
        float4 b1v = *(const float4*)&b[c * 8 + 4];
        union { __half2 h2v[4]; uint4 u; } pk;
        pk.h2v[0] = __floats2half2_rn(fmaxf(a0 * dd + b0v.x, 0.f),
                                      fmaxf(a1 * dd + b0v.y, 0.f));
        pk.h2v[1] = __floats2half2_rn(fmaxf(a2 * dd + b0v.z, 0.f),
                                      fmaxf(a3 * dd + b0v.w, 0.f));
        pk.h2v[2] = __floats2half2_rn(fmaxf(a4 * dd + b1v.x, 0.f),
                                      fmaxf(a5 * dd + b1v.y, 0.f));
        pk.h2v[3] = __floats2half2_rn(fmaxf(a6 * dd + b1v.z, 0.f),
                                      fmaxf(a7 * dd + b1v.w, 0.f));
        *(uint4*)&out[(size_t)wid * HID_DIM + c * 8] = pk.u;
    }
}

// K6: g2 = dinv * (a @ W2)  [50000,64]x[64,40]; fp16 in, fp16 out [N][40]
__global__ void k_gemm2(const __half* __restrict__ a, const float* __restrict__ W2,
                        const float* __restrict__ dinv, __half* __restrict__ g2) {
    int idx = blockIdx.x * blockDim.x + threadIdx.x;
    if (idx >= N_NODES * (OUT_DIM / 4)) return;
    int row = idx / (OUT_DIM / 4);
    int cg  = idx - row * (OUT_DIM / 4);
    const uint2* ar = (const uint2*)(a + (size_t)row * HID_DIM);
    float4 acc = make_float4(0.f, 0.f, 0.f, 0.f);
#pragma unroll
    for (int kk = 0; kk < 16; ++kk) {
        uint2 hv = ar[kk];
        float2 f0 = __half22float2(*(const __half2*)&hv.x);
        float2 f1 = __half22float2(*(const __half2*)&hv.y);
        float4 w0 = *(const float4*)&W2[(kk * 4 + 0) * OUT_DIM + cg * 4];
        float4 w1 = *(const float4*)&W2[(kk * 4 + 1) * OUT_DIM + cg * 4];
        float4 w2 = *(const float4*)&W2[(kk * 4 + 2) * OUT_DIM + cg * 4];
        float4 w3 = *(const float4*)&W2[(kk * 4 + 3) * OUT_DIM + cg * 4];
        acc.x += f0.x * w0.x + f0.y * w1.x + f1.x * w2.x + f1.y * w3.x;
        acc.y += f0.x * w0.y + f0.y * w1.y + f1.x * w2.y + f1.y * w3.y;
        acc.z += f0.x * w0.z + f0.y * w1.z + f1.x * w2.z + f1.y * w3.z;
        acc.w += f0.x * w0.w + f0.y * w1.w + f1.x * w2.w + f1.y * w3.w;
    }
    float dv = dinv[row];
    union { __half2 h2v[2]; uint2 u; } pk;
    pk.h2v[0] = __floats2half2_rn(acc.x * dv, acc.y * dv);
    pk.h2v[1] = __floats2half2_rn(acc.z * dv, acc.w * dv);
    *(uint2*)&g2[(size_t)row * OUT_DIM + cg * 4] = pk.u;
}

// K7: layer-2 aggregation (pre-scaled fp16 in), fused bias + log_softmax.
__global__ __launch_bounds__(256) void k_agg_lsm(const int* __restrict__ rowptr,
        const unsigned short* __restrict__ esrc, const float* __restrict__ dinv,
        const uint2* __restrict__ g,        // [N][10] uint2 (=40 half)
        const float* __restrict__ b,
        float* __restrict__ out) {
    int wid  = (int)((blockIdx.x * (size_t)blockDim.x + threadIdx.x) >> 6);
    int lane = threadIdx.x & 63;
    if (wid >= N_NODES) return;
    int p = lane >> 4;
    int c = lane & 15;
    bool act = (c < 10);
    float ax = 0.f, ay = 0.f, az = 0.f, aw = 0.f;
#define ACC_U2(v)  do {                                            \
        float2 f0 = __half22float2(*(const __half2*)&(v).x);       \
        float2 f1 = __half22float2(*(const __half2*)&(v).y);       \
        ax += f0.x; ay += f0.y; az += f1.x; aw += f1.y; } while (0)
    if (p == 0 && act) { uint2 v = g[(size_t)wid * 10 + c]; ACC_U2(v); }
    int beg = rowptr[wid], deg = rowptr[wid + 1] - beg;
    for (int base = 0; base < deg; base += 64) {          // uniform
        int nb = deg - base; if (nb > 64) nb = 64;        // uniform
        int idx = (lane < nb) ? (int)esrc[beg + base + lane] : 0;
        for (int eb = 0; eb < nb; eb += 16) {             // uniform bound
            int e0 = eb + p;
            int s0 = __shfl(idx, e0);
            int s1 = __shfl(idx, e0 + 4);
            int s2 = __shfl(idx, e0 + 8);
            int s3 = __shfl(idx, e0 + 12);
            if (act) {
                if (e0 + 12 < nb) {
                    uint2 v0 = g[(size_t)s0 * 10 + c];
                    uint2 v1 = g[(size_t)s1 * 10 + c];
                    uint2 v2 = g[(size_t)s2 * 10 + c];
                    uint2 v3 = g[(size_t)s3 * 10 + c];
                    ACC_U2(v0); ACC_U2(v1); ACC_U2(v2); ACC_U2(v3);
                } else {
                    if (e0      < nb) { uint2 v = g[(size_t)s0 * 10 + c]; ACC_U2(v); }
                    if (e0 + 4  < nb) { uint2 v = g[(size_t)s1 * 10 + c]; ACC_U2(v); }
                    if (e0 + 8  < nb) { uint2 v = g[(size_t)s2 * 10 + c]; ACC_U2(v); }
                }
            }
        }
    }
#undef ACC_U2
    ax += __shfl_xor(ax, 16); ax += __shfl_xor(ax, 32);
    ay += __shfl_xor(ay, 16); ay += __shfl_xor(ay, 32);
    az += __shfl_xor(az, 16); az += __shfl_xor(az, 32);
    aw += __shfl_xor(aw, 16); aw += __shfl_xor(aw, 32);
    float dd = dinv[wid];
    float vx = -INFINITY, vy = -INFINITY, vz = -INFINITY, vw = -INFINITY;
    if (act) {
        float4 bb = *(const float4*)&b[c * 4];
        vx = ax * dd + bb.x; vy = ay * dd + bb.y;
        vz = az * dd + bb.z; vw = aw * dd + bb.w;
    }
    float m = fmaxf(fmaxf(vx, vy), fmaxf(vz, vw));
    for (int o = 8; o; o >>= 1) m = fmaxf(m, __shfl_xor(m, o));
    float es = act ? (__expf(vx - m) + __expf(vy - m) + __expf(vz - m) + __expf(vw - m)) : 0.f;
    for (int o = 8; o; o >>= 1) es += __shfl_xor(es, o);
    float ls = __logf(es);
    if (lane < 16 && act) {
        float4 o4 = make_float4(vx - m - ls, vy - m - ls, vz - m - ls, vw - m - ls);
        *(float4*)&out[(size_t)wid * OUT_DIM + c * 4] = o4;
    }
}

extern "C" void kernel_launch(void* const* d_in, const int* in_sizes, int n_in,
                              void* d_out, int out_size, void* d_ws, size_t ws_size,
                              hipStream_t stream) {
    const float* x    = (const float*)d_in[0];
    const int*   ei   = (const int*)d_in[1];
    const int*   srcp = ei;             // edge_index[0]
    const int*   dstp = ei + N_EDGES;   // edge_index[1]
    const float* W1   = (const float*)d_in[2];
    const float* b1   = (const float*)d_in[3];
    const float* W2   = (const float*)d_in[4];
    const float* b2   = (const float*)d_in[5];
    float* out = (float*)d_out;

    // workspace layout (~25 MB)
    char* p = (char*)d_ws;
    int*            hist   = (int*)p;            p += (size_t)EH_BLOCKS * NBINS * 4;
    int*            total  = (int*)p;            p += 256 * 4;
    int*            rowptr = (int*)p;            p += (size_t)(N_NODES + 4) * 4;
    unsigned int*   packed = (unsigned int*)p;   p += (size_t)N_EDGES * 4;
    unsigned short* esrc   = (unsigned short*)p; p += (size_t)N_EDGES * 2;
    float*          dinv   = (float*)p;          p += (size_t)N_NODES * 4;
    __half*         w1t    = (__half*)p;         p += (size_t)IN_DIM * HID_DIM * 2;
    __half*         g1     = (__half*)p;         p += (size_t)N_NODES * HID_DIM * 2;
    __half*         agg1   = (__half*)p;         p += (size_t)N_NODES * HID_DIM * 2;
    __half*         g2     = (__half*)p;         p += (size_t)N_NODES * OUT_DIM * 2;

    k_init<<<64, 256, 0, stream>>>(W1, w1t);

    k_gemm1_hist<<<GEMM1_BLOCKS + EH_BLOCKS, 256, 0, stream>>>(
        x, w1t, g1, dstp, hist);

    k_scanbins<<<NBINS, 256, 0, stream>>>(hist, total);

    k_scatter1<<<EH_BLOCKS, 256, 0, stream>>>(srcp, dstp, hist, total, packed);

    k_build<<<NBINS, 256, 0, stream>>>(packed, total, rowptr, dinv, esrc, g1);

    k_agg_relu<<<(N_NODES + 3) / 4, 256, 0, stream>>>(rowptr, esrc, dinv,
                                                      (const uint4*)g1, b1, agg1);

    k_gemm2<<<(N_NODES * (OUT_DIM / 4) + 255) / 256, 256, 0, stream>>>(agg1, W2, dinv, g2);

    k_agg_lsm<<<(N_NODES + 3) / 4, 256, 0, stream>>>(rowptr, esrc, dinv,
                                                     (const uint2*)g2, b2, out);
}

// Round 24
// 129.565 us; speedup vs baseline: 1.0743x; 1.0506x over previous
//
#include <hip/hip_runtime.h>
#include <hip/hip_bf16.h>
#include <hip/hip_fp16.h>
#include <cstddef>

#define N_NODES 50000
#define IN_DIM 256
#define HID_DIM 64
#define OUT_DIM 40
#define N_EDGES 800000
#define NBINS 196           // ceil(N_NODES / 256); bin(d) = d >> 8
#define GEMM1_BLOCKS 782    // ceil(N_NODES / 64)
#define EH_BLOCKS 3125      // ceil(N_EDGES / 256)
#define INIT_BLOCKS 64      // w1t conversion

typedef _Float16 f16x8 __attribute__((ext_vector_type(8)));
typedef float f32x4 __attribute__((ext_vector_type(4)));

// ---------------------------------------------------------------------------
// K0: FUSED w1t build + coarse histogram. Blocks [0,64) = w1t; blocks
// [64, 64+EH_BLOCKS) = per-block 196-bin LDS histogram of dst>>8.
// (hist depends only on dst; independent of init.)
__global__ __launch_bounds__(256) void k_init_hist(
        const float* __restrict__ W1, __half* __restrict__ w1t,
        const int* __restrict__ dst, int* __restrict__ hist) {
    __shared__ int lh[NBINS];
    const int tid = threadIdx.x;
    if (blockIdx.x >= INIT_BLOCKS) {             // ---- hist path ----
        if (tid < NBINS) lh[tid] = 0;
        __syncthreads();
        int i = (blockIdx.x - INIT_BLOCKS) * 256 + tid;
        if (i < N_EDGES) atomicAdd(&lh[dst[i] >> 8], 1);   // LDS atomic
        __syncthreads();
        if (tid < NBINS)
            hist[(size_t)(blockIdx.x - INIT_BLOCKS) * NBINS + tid] = lh[tid];
        return;
    }
    int i = blockIdx.x * 256 + tid;
    if (i < IN_DIM * HID_DIM) {
        int c = i >> 8, k = i & 255;
        w1t[i] = __float2half(W1[(size_t)k * HID_DIM + c]);
    }
}

// K1: FUSED gemm1 (UNSCALED g1) + per-bin column scan of hist.
// Blocks [0, GEMM1_BLOCKS) = gemm1; blocks [GEMM1_BLOCKS, +NBINS) = scanbins.
// (scanbins depends only on hist from launch 1; gemm1 needs w1t.)
__global__ __launch_bounds__(256) void k_gemm1_scan(
        const float* __restrict__ x, const __half* __restrict__ w1t,
        __half* __restrict__ g1,
        int* __restrict__ hist, int* __restrict__ total) {
    __shared__ _Float16 xh[64][72];   // 18 KB; scan path uses first 16 B
    __shared__ _Float16 wt[64][72];
    const int tid = threadIdx.x;
    if (blockIdx.x >= GEMM1_BLOCKS) {            // ---- scanbins path ----
        int* wsum = (int*)&xh[0][0];             // 4 ints
        const int b = blockIdx.x - GEMM1_BLOCKS;
        const int lane = tid & 63, w = tid >> 6;
        int vals[13];
        int lsum = 0;
#pragma unroll
        for (int i = 0; i < 13; ++i) {
            int j = tid * 13 + i;
            vals[i] = (j < EH_BLOCKS) ? hist[(size_t)j * NBINS + b] : 0;
            lsum += vals[i];
        }
        int inc = lsum;
#pragma unroll
        for (int o = 1; o < 64; o <<= 1) {
            int u = __shfl_up(inc, o);
            if (lane >= o) inc += u;
        }
        if (lane == 63) wsum[w] = inc;
        __syncthreads();
        int off = 0;
        for (int k = 0; k < w; ++k) off += wsum[k];
        int run = off + inc - lsum;
#pragma unroll
        for (int i = 0; i < 13; ++i) {
            int j = tid * 13 + i;
            if (j < EH_BLOCKS) hist[(size_t)j * NBINS + b] = run;
            run += vals[i];
        }
        if (tid == 255) total[b] = run;
        return;
    }
    // ---- gemm1 path (four K=64 phases, 18 KB LDS) ----
    const int row0 = blockIdx.x * 64;
    const int r = tid >> 2, q = tid & 3;
    const int wv = tid >> 6, l = tid & 63;
    const int rowa = wv * 16 + (l & 15);
    const int koff = (l >> 4) * 8;
    const int grow_s = row0 + r;
    f32x4 acc0 = {0.f, 0.f, 0.f, 0.f}, acc1 = acc0, acc2 = acc0, acc3 = acc0;
#pragma unroll
    for (int kh = 0; kh < 4; ++kh) {
        __syncthreads();
        {
            const uint4* wsrc = (const uint4*)(w1t + (size_t)r * 256 + kh * 64 + q * 16);
            uint4* wdst = (uint4*)&wt[r][q * 16];
            wdst[0] = wsrc[0];
            wdst[1] = wsrc[1];
            const float4* xsrc = (const float4*)(x + (size_t)grow_s * IN_DIM + kh * 64 + q * 16);
#pragma unroll
            for (int i = 0; i < 2; ++i) {
                float4 f0 = make_float4(0.f, 0.f, 0.f, 0.f), f1 = f0;
                if (grow_s < N_NODES) { f0 = xsrc[2 * i]; f1 = xsrc[2 * i + 1]; }
                f16x8 v;
                v[0] = (_Float16)f0.x; v[1] = (_Float16)f0.y;
                v[2] = (_Float16)f0.z; v[3] = (_Float16)f0.w;
                v[4] = (_Float16)f1.x; v[5] = (_Float16)f1.y;
                v[6] = (_Float16)f1.z; v[7] = (_Float16)f1.w;
                *(f16x8*)&xh[r][q * 16 + i * 8] = v;
            }
        }
        __syncthreads();
#pragma unroll
        for (int ks = 0; ks < 2; ++ks) {
            f16x8 a  = *(const f16x8*)&xh[rowa][ks * 32 + koff];
            f16x8 b0 = *(const f16x8*)&wt[ 0 + (l & 15)][ks * 32 + koff];
            f16x8 b1 = *(const f16x8*)&wt[16 + (l & 15)][ks * 32 + koff];
            f16x8 b2 = *(const f16x8*)&wt[32 + (l & 15)][ks * 32 + koff];
            f16x8 b3 = *(const f16x8*)&wt[48 + (l & 15)][ks * 32 + koff];
            acc0 = __builtin_amdgcn_mfma_f32_16x16x32_f16(a, b0, acc0, 0, 0, 0);
            acc1 = __builtin_amdgcn_mfma_f32_16x16x32_f16(a, b1, acc1, 0, 0, 0);
            acc2 = __builtin_amdgcn_mfma_f32_16x16x32_f16(a, b2, acc2, 0, 0, 0);
            acc3 = __builtin_amdgcn_mfma_f32_16x16x32_f16(a, b3, acc3, 0, 0, 0);
        }
    }
    // C/D: col = lane&15, row = (lane>>4)*4 + reg  [m89-verified]
    const int colc = l & 15;
#pragma unroll
    for (int rr = 0; rr < 4; ++rr) {
        int grow = row0 + wv * 16 + (l >> 4) * 4 + rr;
        if (grow < N_NODES) {
            __half* dst2 = g1 + (size_t)grow * HID_DIM;
            dst2[ 0 + colc] = __float2half(acc0[rr]);
            dst2[16 + colc] = __float2half(acc1[rr]);
            dst2[32 + colc] = __float2half(acc2[rr]);
            dst2[48 + colc] = __float2half(acc3[rr]);
        }
    }
}

// K2: scatter edges into bucket-grouped packed array (LDS atomics only).
// packed = dst<<16 | src (both < 65536).
__global__ __launch_bounds__(256) void k_scatter1(
        const int* __restrict__ src, const int* __restrict__ dst,
        const int* __restrict__ hist, const int* __restrict__ total,
        unsigned int* __restrict__ packed) {
    __shared__ int wsum[4];
    __shared__ int cursor[NBINS];
    const int t = threadIdx.x;
    const int lane = t & 63, w = t >> 6;
    int v = (t < NBINS) ? total[t] : 0;
    int inc = v;
#pragma unroll
    for (int o = 1; o < 64; o <<= 1) {
        int u = __shfl_up(inc, o);
        if (lane >= o) inc += u;
    }
    if (lane == 63) wsum[w] = inc;
    __syncthreads();
    int off = 0;
    for (int k = 0; k < w; ++k) off += wsum[k];
    int excl = off + inc - v;
    if (t < NBINS)
        cursor[t] = excl + hist[(size_t)blockIdx.x * NBINS + t];
    __syncthreads();
    int i = blockIdx.x * 256 + t;
    if (i < N_EDGES) {
        int d = dst[i], s = src[i];
        int pos = atomicAdd(&cursor[d >> 8], 1);          // LDS atomic
        packed[pos] = ((unsigned)d << 16) | (unsigned)s;
    }
}

// K3: per-bin CSR build + g1 scale (R23-proven).
__global__ __launch_bounds__(256) void k_build(
        const unsigned int* __restrict__ packed, const int* __restrict__ total,
        int* __restrict__ rowptr, float* __restrict__ dinv,
        unsigned short* __restrict__ esrc, __half* __restrict__ g1) {
    __shared__ int wsum[4];
    __shared__ int degl[256];
    __shared__ int curl[256];
    __shared__ float dinvl[256];
    __shared__ int bs2[2];
    const int b = blockIdx.x, t = threadIdx.x;
    const int lane = t & 63, w = t >> 6;
    {
        int v = (t < NBINS) ? total[t] : 0;
        int inc = v;
#pragma unroll
        for (int o = 1; o < 64; o <<= 1) {
            int u = __shfl_up(inc, o);
            if (lane >= o) inc += u;
        }
        if (lane == 63) wsum[w] = inc;
        __syncthreads();
        int off = 0;
        for (int k = 0; k < w; ++k) off += wsum[k];
        int excl = off + inc - v;
        if (t == b) bs2[0] = excl;
        if (t == b + 1) bs2[1] = excl;
        degl[t] = 0;
    }
    __syncthreads();
    const int s0 = bs2[0], s1 = bs2[1];
    for (int e = s0 + t; e < s1; e += 256)
        atomicAdd(&degl[(packed[e] >> 16) & 255], 1);
    __syncthreads();
    int dv = degl[t];
    {
        int inc = dv;
#pragma unroll
        for (int o = 1; o < 64; o <<= 1) {
            int u = __shfl_up(inc, o);
            if (lane >= o) inc += u;
        }
        if (lane == 63) wsum[w] = inc;
        __syncthreads();
        int off = 0;
        for (int k = 0; k < w; ++k) off += wsum[k];
        int excl = off + inc - dv;
        int node = b * 256 + t;
        float di = rsqrtf((float)dv + 1.0f);
        if (node < N_NODES) {
            rowptr[node] = s0 + excl;
            dinv[node] = di;
        }
        if (node == N_NODES) rowptr[N_NODES] = N_EDGES;
        dinvl[t] = di;
        curl[t] = excl;
    }
    __syncthreads();
    for (int e = s0 + t; e < s1; e += 256) {
        unsigned pk = packed[e];
        int ln = (pk >> 16) & 255;
        int pos = s0 + atomicAdd(&curl[ln], 1);
        esrc[pos] = (unsigned short)(pk & 0xFFFFu);
    }
    for (int idx = t; idx < 256 * 8; idx += 256) {
        int ln = idx >> 3;
        int node = b * 256 + ln;
        if (node < N_NODES) {
            float di = dinvl[ln];
            uint4 v4 = *(uint4*)&g1[(size_t)node * HID_DIM + (idx & 7) * 8];
            union { __half2 h2v[4]; uint4 u; } pk2;
            const __half2* hv = (const __half2*)&v4;
#pragma unroll
            for (int i = 0; i < 4; ++i) {
                float2 f = __half22float2(hv[i]);
                pk2.h2v[i] = __floats2half2_rn(f.x * di, f.y * di);
            }
            *(uint4*)&g1[(size_t)node * HID_DIM + (idx & 7) * 8] = pk2.u;
        }
    }
}

// K4: gather aggregation DIM=64 (pre-scaled fp16 in), fused bias+ReLU,
// fp16 output. uint4 structure: 8 parities x 8 lanes x 16B.
__global__ __launch_bounds__(256) void k_agg_relu(const int* __restrict__ rowptr,
        const unsigned short* __restrict__ esrc, const float* __restrict__ dinv,
        const uint4* __restrict__ g,        // [N][8] uint4 (=64 half)
        const float* __restrict__ b,
        __half* __restrict__ out) {         // agg1 [N][64] fp16
    int wid  = (int)((blockIdx.x * (size_t)blockDim.x + threadIdx.x) >> 6);
    int lane = threadIdx.x & 63;
    if (wid >= N_NODES) return;
    int p = lane >> 3;        // edge parity 0..7
    int c = lane & 7;         // uint4 channel group (8 halves)
    float a0 = 0.f, a1 = 0.f, a2 = 0.f, a3 = 0.f;
    float a4 = 0.f, a5 = 0.f, a6 = 0.f, a7 = 0.f;
#define ACC_U4(v)  do {                                            \
        float2 f0 = __half22float2(*(const __half2*)&(v).x);       \
        float2 f1 = __half22float2(*(const __half2*)&(v).y);       \
        float2 f2 = __half22float2(*(const __half2*)&(v).z);       \
        float2 f3 = __half22float2(*(const __half2*)&(v).w);       \
        a0 += f0.x; a1 += f0.y; a2 += f1.x; a3 += f1.y;            \
        a4 += f2.x; a5 += f2.y; a6 += f3.x; a7 += f3.y; } while (0)
    if (p == 0) { uint4 v = g[(size_t)wid * 8 + c]; ACC_U4(v); }   // self-loop
    int beg = rowptr[wid], deg = rowptr[wid + 1] - beg;
    for (int base = 0; base < deg; base += 64) {          // uniform
        int nb = deg - base; if (nb > 64) nb = 64;        // uniform
        int idx = (lane < nb) ? (int)esrc[beg + base + lane] : 0;  // coalesced
        for (int eb = 0; eb < nb; eb += 32) {             // uniform bound
            int e0 = eb + p;                              // e0+24 <= 63 always
            int s0 = __shfl(idx, e0);
            int s1 = __shfl(idx, e0 + 8);
            int s2 = __shfl(idx, e0 + 16);
            int s3 = __shfl(idx, e0 + 24);
            if (e0 + 24 < nb) {                           // fast path: all 4
                uint4 v0 = g[(size_t)s0 * 8 + c];
                uint4 v1 = g[(size_t)s1 * 8 + c];
                uint4 v2 = g[(size_t)s2 * 8 + c];
                uint4 v3 = g[(size_t)s3 * 8 + c];
                ACC_U4(v0); ACC_U4(v1); ACC_U4(v2); ACC_U4(v3);
            } else {                                      // tail: per-edge guard
                if (e0      < nb) { uint4 v = g[(size_t)s0 * 8 + c]; ACC_U4(v); }
                if (e0 + 8  < nb) { uint4 v = g[(size_t)s1 * 8 + c]; ACC_U4(v); }
                if (e0 + 16 < nb) { uint4 v = g[(size_t)s2 * 8 + c]; ACC_U4(v); }
            }
        }
    }
#undef ACC_U4
    a0 += __shfl_xor(a0, 8); a0 += __shfl_xor(a0, 16); a0 += __shfl_xor(a0, 32);
    a1 += __shfl_xor(a1, 8); a1 += __shfl_xor(a1, 16); a1 += __shfl_xor(a1, 32);
    a2 += __shfl_xor(a2, 8); a2 += __shfl_xor(a2, 16); a2 += __shfl_xor(a2, 32);
    a3 += __shfl_xor(a3, 8); a3 += __shfl_xor(a3, 16); a3 += __shfl_xor(a3, 32);
    a4 += __shfl_xor(a4, 8); a4 += __shfl_xor(a4, 16); a4 += __shfl_xor(a4, 32);
    a5 += __shfl_xor(a5, 8); a5 += __shfl_xor(a5, 16); a5 += __shfl_xor(a5, 32);
    a6 += __shfl_xor(a6, 8); a6 += __shfl_xor(a6, 16); a6 += __shfl_xor(a6, 32);
    a7 += __shfl_xor(a7, 8); a7 += __shfl_xor(a7, 16); a7 += __shfl_xor(a7, 32);
    if (lane < 8) {
        float dd = dinv[wid];
        float4 b0v = *(const float4*)&b[c * 8 + 0];
        float4 b1v = *(const float4*)&b[c * 8 + 4];
        union { __half2 h2v[4]; uint4 u; } pk;
        pk.h2v[0] = __floats2half2_rn(fmaxf(a0 * dd + b0v.x, 0.f),
                                      fmaxf(a1 * dd + b0v.y, 0.f));
        pk.h2v[1] = __floats2half2_rn(fmaxf(a2 * dd + b0v.z, 0.f),
                                      fmaxf(a3 * dd + b0v.w, 0.f));
        pk.h2v[2] = __floats2half2_rn(fmaxf(a4 * dd + b1v.x, 0.f),
                                      fmaxf(a5 * dd + b1v.y, 0.f));
        pk.h2v[3] = __floats2half2_rn(fmaxf(a6 * dd + b1v.z, 0.f),
                                      fmaxf(a7 * dd + b1v.w, 0.f));
        *(uint4*)&out[(size_t)wid * HID_DIM + c * 8] = pk.u;
    }
}

// K5: g2 = dinv * (a @ W2)  [50000,64]x[64,40]; fp16 in, fp16 out [N][40]
__global__ void k_gemm2(const __half* __restrict__ a, const float* __restrict__ W2,
                        const float* __restrict__ dinv, __half* __restrict__ g2) {
    int idx = blockIdx.x * blockDim.x + threadIdx.x;
    if (idx >= N_NODES * (OUT_DIM / 4)) return;
    int row = idx / (OUT_DIM / 4);
    int cg  = idx - row * (OUT_DIM / 4);
    const uint2* ar = (const uint2*)(a + (size_t)row * HID_DIM);
    float4 acc = make_float4(0.f, 0.f, 0.f, 0.f);
#pragma unroll
    for (int kk = 0; kk < 16; ++kk) {
        uint2 hv = ar[kk];
        float2 f0 = __half22float2(*(const __half2*)&hv.x);
        float2 f1 = __half22float2(*(const __half2*)&hv.y);
        float4 w0 = *(const float4*)&W2[(kk * 4 + 0) * OUT_DIM + cg * 4];
        float4 w1 = *(const float4*)&W2[(kk * 4 + 1) * OUT_DIM + cg * 4];
        float4 w2 = *(const float4*)&W2[(kk * 4 + 2) * OUT_DIM + cg * 4];
        float4 w3 = *(const float4*)&W2[(kk * 4 + 3) * OUT_DIM + cg * 4];
        acc.x += f0.x * w0.x + f0.y * w1.x + f1.x * w2.x + f1.y * w3.x;
        acc.y += f0.x * w0.y + f0.y * w1.y + f1.x * w2.y + f1.y * w3.y;
        acc.z += f0.x * w0.z + f0.y * w1.z + f1.x * w2.z + f1.y * w3.z;
        acc.w += f0.x * w0.w + f0.y * w1.w + f1.x * w2.w + f1.y * w3.w;
    }
    float dv = dinv[row];
    union { __half2 h2v[2]; uint2 u; } pk;
    pk.h2v[0] = __floats2half2_rn(acc.x * dv, acc.y * dv);
    pk.h2v[1] = __floats2half2_rn(acc.z * dv, acc.w * dv);
    *(uint2*)&g2[(size_t)row * OUT_DIM + cg * 4] = pk.u;
}

// K6: layer-2 aggregation (pre-scaled fp16 in), fused bias + log_softmax.
__global__ __launch_bounds__(256) void k_agg_lsm(const int* __restrict__ rowptr,
        const unsigned short* __restrict__ esrc, const float* __restrict__ dinv,
        const uint2* __restrict__ g,        // [N][10] uint2 (=40 half)
        const float* __restrict__ b,
        float* __restrict__ out) {
    int wid  = (int)((blockIdx.x * (size_t)blockDim.x + threadIdx.x) >> 6);
    int lane = threadIdx.x & 63;
    if (wid >= N_NODES) return;
    int p = lane >> 4;
    int c = lane & 15;
    bool act = (c < 10);
    float ax = 0.f, ay = 0.f, az = 0.f, aw = 0.f;
#define ACC_U2(v)  do {                                            \
        float2 f0 = __half22float2(*(const __half2*)&(v).x);       \
        float2 f1 = __half22float2(*(const __half2*)&(v).y);       \
        ax += f0.x; ay += f0.y; az += f1.x; aw += f1.y; } while (0)
    if (p == 0 && act) { uint2 v = g[(size_t)wid * 10 + c]; ACC_U2(v); }
    int beg = rowptr[wid], deg = rowptr[wid + 1] - beg;
    for (int base = 0; base < deg; base += 64) {          // uniform
        int nb = deg - base; if (nb > 64) nb = 64;        // uniform
        int idx = (lane < nb) ? (int)esrc[beg + base + lane] : 0;
        for (int eb = 0; eb < nb; eb += 16) {             // uniform bound
            int e0 = eb + p;
            int s0 = __shfl(idx, e0);
            int s1 = __shfl(idx, e0 + 4);
            int s2 = __shfl(idx, e0 + 8);
            int s3 = __shfl(idx, e0 + 12);
            if (act) {
                if (e0 + 12 < nb) {
                    uint2 v0 = g[(size_t)s0 * 10 + c];
                    uint2 v1 = g[(size_t)s1 * 10 + c];
                    uint2 v2 = g[(size_t)s2 * 10 + c];
                    uint2 v3 = g[(size_t)s3 * 10 + c];
                    ACC_U2(v0); ACC_U2(v1); ACC_U2(v2); ACC_U2(v3);
                } else {
                    if (e0      < nb) { uint2 v = g[(size_t)s0 * 10 + c]; ACC_U2(v); }
                    if (e0 + 4  < nb) { uint2 v = g[(size_t)s1 * 10 + c]; ACC_U2(v); }
                    if (e0 + 8  < nb) { uint2 v = g[(size_t)s2 * 10 + c]; ACC_U2(v); }
                }
            }
        }
    }
#undef ACC_U2
    ax += __shfl_xor(ax, 16); ax += __shfl_xor(ax, 32);
    ay += __shfl_xor(ay, 16); ay += __shfl_xor(ay, 32);
    az += __shfl_xor(az, 16); az += __shfl_xor(az, 32);
    aw += __shfl_xor(aw, 16); aw += __shfl_xor(aw, 32);
    float dd = dinv[wid];
    float vx = -INFINITY, vy = -INFINITY, vz = -INFINITY, vw = -INFINITY;
    if (act) {
        float4 bb = *(const float4*)&b[c * 4];
        vx = ax * dd + bb.x; vy = ay * dd + bb.y;
        vz = az * dd + bb.z; vw = aw * dd + bb.w;
    }
    float m = fmaxf(fmaxf(vx, vy), fmaxf(vz, vw));
    for (int o = 8; o; o >>= 1) m = fmaxf(m, __shfl_xor(m, o));
    float es = act ? (__expf(vx - m) + __expf(vy - m) + __expf(vz - m) + __expf(vw - m)) : 0.f;
    for (int o = 8; o; o >>= 1) es += __shfl_xor(es, o);
    float ls = __logf(es);
    if (lane < 16 && act) {
        float4 o4 = make_float4(vx - m - ls, vy - m - ls, vz - m - ls, vw - m - ls);
        *(float4*)&out[(size_t)wid * OUT_DIM + c * 4] = o4;
    }
}

extern "C" void kernel_launch(void* const* d_in, const int* in_sizes, int n_in,
                              void* d_out, int out_size, void* d_ws, size_t ws_size,
                              hipStream_t stream) {
    const float* x    = (const float*)d_in[0];
    const int*   ei   = (const int*)d_in[1];
    const int*   srcp = ei;             // edge_index[0]
    const int*   dstp = ei + N_EDGES;   // edge_index[1]
    const float* W1   = (const float*)d_in[2];
    const float* b1   = (const float*)d_in[3];
    const float* W2   = (const float*)d_in[4];
    const float* b2   = (const float*)d_in[5];
    float* out = (float*)d_out;

    // workspace layout (~25 MB)
    char* p = (char*)d_ws;
    int*            hist   = (int*)p;            p += (size_t)EH_BLOCKS * NBINS * 4;
    int*            total  = (int*)p;            p += 256 * 4;
    int*            rowptr = (int*)p;            p += (size_t)(N_NODES + 4) * 4;
    unsigned int*   packed = (unsigned int*)p;   p += (size_t)N_EDGES * 4;
    unsigned short* esrc   = (unsigned short*)p; p += (size_t)N_EDGES * 2;
    float*          dinv   = (float*)p;          p += (size_t)N_NODES * 4;
    __half*         w1t    = (__half*)p;         p += (size_t)IN_DIM * HID_DIM * 2;
    __half*         g1     = (__half*)p;         p += (size_t)N_NODES * HID_DIM * 2;
    __half*         agg1   = (__half*)p;         p += (size_t)N_NODES * HID_DIM * 2;
    __half*         g2     = (__half*)p;         p += (size_t)N_NODES * OUT_DIM * 2;

    k_init_hist<<<INIT_BLOCKS + EH_BLOCKS, 256, 0, stream>>>(W1, w1t, dstp, hist);

    k_gemm1_scan<<<GEMM1_BLOCKS + NBINS, 256, 0, stream>>>(x, w1t, g1, hist, total);

    k_scatter1<<<EH_BLOCKS, 256, 0, stream>>>(srcp, dstp, hist, total, packed);

    k_build<<<NBINS, 256, 0, stream>>>(packed, total, rowptr, dinv, esrc, g1);

    k_agg_relu<<<(N_NODES + 3) / 4, 256, 0, stream>>>(rowptr, esrc, dinv,
                                                      (const uint4*)g1, b1, agg1);

    k_gemm2<<<(N_NODES * (OUT_DIM / 4) + 255) / 256, 256, 0, stream>>>(agg1, W2, dinv, g2);

    k_agg_lsm<<<(N_NODES + 3) / 4, 256, 0, stream>>>(rowptr, esrc, dinv,
                                                     (const uint2*)g2, b2, out);
}

// Round 25
// 118.401 us; speedup vs baseline: 1.1755x; 1.0943x over previous
//
#include <hip/hip_runtime.h>
#include <hip/hip_bf16.h>
#include <hip/hip_fp16.h>
#include <cstddef>

#define N_NODES 50000
#define IN_DIM 256
#define HID_DIM 64
#define OUT_DIM 40
#define N_EDGES 800000
#define NBINS 196           // ceil(N_NODES / 256); bin(d) = d >> 8
#define GEMM1_BLOCKS 782    // ceil(N_NODES / 64)
#define EH_BLOCKS 3125      // ceil(N_EDGES / 256)
#define INIT_BLOCKS 64      // w1t conversion

typedef _Float16 f16x8 __attribute__((ext_vector_type(8)));
typedef float f32x4 __attribute__((ext_vector_type(4)));

// ---------------------------------------------------------------------------
// K0: FUSED w1t build + coarse histogram (dst>>8), LDS atomics only.
__global__ __launch_bounds__(256) void k_init_hist(
        const float* __restrict__ W1, __half* __restrict__ w1t,
        const int* __restrict__ dst, int* __restrict__ hist) {
    __shared__ int lh[NBINS];
    const int tid = threadIdx.x;
    if (blockIdx.x >= INIT_BLOCKS) {             // ---- hist path ----
        if (tid < NBINS) lh[tid] = 0;
        __syncthreads();
        int i = (blockIdx.x - INIT_BLOCKS) * 256 + tid;
        if (i < N_EDGES) atomicAdd(&lh[dst[i] >> 8], 1);   // LDS atomic
        __syncthreads();
        if (tid < NBINS)
            hist[(size_t)(blockIdx.x - INIT_BLOCKS) * NBINS + tid] = lh[tid];
        return;
    }
    int i = blockIdx.x * 256 + tid;
    if (i < IN_DIM * HID_DIM) {
        int c = i >> 8, k = i & 255;
        w1t[i] = __float2half(W1[(size_t)k * HID_DIM + c]);
    }
}

// K1: FUSED gemm1 (UNSCALED g1) + per-bin column scan of hist.
__global__ __launch_bounds__(256) void k_gemm1_scan(
        const float* __restrict__ x, const __half* __restrict__ w1t,
        __half* __restrict__ g1,
        int* __restrict__ hist, int* __restrict__ total) {
    __shared__ _Float16 xh[64][72];   // 18 KB; scan path uses first 16 B
    __shared__ _Float16 wt[64][72];
    const int tid = threadIdx.x;
    if (blockIdx.x >= GEMM1_BLOCKS) {            // ---- scanbins path ----
        int* wsum = (int*)&xh[0][0];             // 4 ints
        const int b = blockIdx.x - GEMM1_BLOCKS;
        const int lane = tid & 63, w = tid >> 6;
        int vals[13];
        int lsum = 0;
#pragma unroll
        for (int i = 0; i < 13; ++i) {
            int j = tid * 13 + i;
            vals[i] = (j < EH_BLOCKS) ? hist[(size_t)j * NBINS + b] : 0;
            lsum += vals[i];
        }
        int inc = lsum;
#pragma unroll
        for (int o = 1; o < 64; o <<= 1) {
            int u = __shfl_up(inc, o);
            if (lane >= o) inc += u;
        }
        if (lane == 63) wsum[w] = inc;
        __syncthreads();
        int off = 0;
        for (int k = 0; k < w; ++k) off += wsum[k];
        int run = off + inc - lsum;
#pragma unroll
        for (int i = 0; i < 13; ++i) {
            int j = tid * 13 + i;
            if (j < EH_BLOCKS) hist[(size_t)j * NBINS + b] = run;
            run += vals[i];
        }
        if (tid == 255) total[b] = run;
        return;
    }
    // ---- gemm1 path (four K=64 phases, 18 KB LDS) ----
    const int row0 = blockIdx.x * 64;
    const int r = tid >> 2, q = tid & 3;
    const int wv = tid >> 6, l = tid & 63;
    const int rowa = wv * 16 + (l & 15);
    const int koff = (l >> 4) * 8;
    const int grow_s = row0 + r;
    f32x4 acc0 = {0.f, 0.f, 0.f, 0.f}, acc1 = acc0, acc2 = acc0, acc3 = acc0;
#pragma unroll
    for (int kh = 0; kh < 4; ++kh) {
        __syncthreads();
        {
            const uint4* wsrc = (const uint4*)(w1t + (size_t)r * 256 + kh * 64 + q * 16);
            uint4* wdst = (uint4*)&wt[r][q * 16];
            wdst[0] = wsrc[0];
            wdst[1] = wsrc[1];
            const float4* xsrc = (const float4*)(x + (size_t)grow_s * IN_DIM + kh * 64 + q * 16);
#pragma unroll
            for (int i = 0; i < 2; ++i) {
                float4 f0 = make_float4(0.f, 0.f, 0.f, 0.f), f1 = f0;
                if (grow_s < N_NODES) { f0 = xsrc[2 * i]; f1 = xsrc[2 * i + 1]; }
                f16x8 v;
                v[0] = (_Float16)f0.x; v[1] = (_Float16)f0.y;
                v[2] = (_Float16)f0.z; v[3] = (_Float16)f0.w;
                v[4] = (_Float16)f1.x; v[5] = (_Float16)f1.y;
                v[6] = (_Float16)f1.z; v[7] = (_Float16)f1.w;
                *(f16x8*)&xh[r][q * 16 + i * 8] = v;
            }
        }
        __syncthreads();
#pragma unroll
        for (int ks = 0; ks < 2; ++ks) {
            f16x8 a  = *(const f16x8*)&xh[rowa][ks * 32 + koff];
            f16x8 b0 = *(const f16x8*)&wt[ 0 + (l & 15)][ks * 32 + koff];
            f16x8 b1 = *(const f16x8*)&wt[16 + (l & 15)][ks * 32 + koff];
            f16x8 b2 = *(const f16x8*)&wt[32 + (l & 15)][ks * 32 + koff];
            f16x8 b3 = *(const f16x8*)&wt[48 + (l & 15)][ks * 32 + koff];
            acc0 = __builtin_amdgcn_mfma_f32_16x16x32_f16(a, b0, acc0, 0, 0, 0);
            acc1 = __builtin_amdgcn_mfma_f32_16x16x32_f16(a, b1, acc1, 0, 0, 0);
            acc2 = __builtin_amdgcn_mfma_f32_16x16x32_f16(a, b2, acc2, 0, 0, 0);
            acc3 = __builtin_amdgcn_mfma_f32_16x16x32_f16(a, b3, acc3, 0, 0, 0);
        }
    }
    // C/D: col = lane&15, row = (lane>>4)*4 + reg  [m89-verified]
    const int colc = l & 15;
#pragma unroll
    for (int rr = 0; rr < 4; ++rr) {
        int grow = row0 + wv * 16 + (l >> 4) * 4 + rr;
        if (grow < N_NODES) {
            __half* dst2 = g1 + (size_t)grow * HID_DIM;
            dst2[ 0 + colc] = __float2half(acc0[rr]);
            dst2[16 + colc] = __float2half(acc1[rr]);
            dst2[32 + colc] = __float2half(acc2[rr]);
            dst2[48 + colc] = __float2half(acc3[rr]);
        }
    }
}

// K2: scatter edges into bucket-grouped packed array (LDS atomics only).
__global__ __launch_bounds__(256) void k_scatter1(
        const int* __restrict__ src, const int* __restrict__ dst,
        const int* __restrict__ hist, const int* __restrict__ total,
        unsigned int* __restrict__ packed) {
    __shared__ int wsum[4];
    __shared__ int cursor[NBINS];
    const int t = threadIdx.x;
    const int lane = t & 63, w = t >> 6;
    int v = (t < NBINS) ? total[t] : 0;
    int inc = v;
#pragma unroll
    for (int o = 1; o < 64; o <<= 1) {
        int u = __shfl_up(inc, o);
        if (lane >= o) inc += u;
    }
    if (lane == 63) wsum[w] = inc;
    __syncthreads();
    int off = 0;
    for (int k = 0; k < w; ++k) off += wsum[k];
    int excl = off + inc - v;
    if (t < NBINS)
        cursor[t] = excl + hist[(size_t)blockIdx.x * NBINS + t];
    __syncthreads();
    int i = blockIdx.x * 256 + t;
    if (i < N_EDGES) {
        int d = dst[i], s = src[i];
        int pos = atomicAdd(&cursor[d >> 8], 1);          // LDS atomic
        packed[pos] = ((unsigned)d << 16) | (unsigned)s;
    }
}

// K3: per-bin CSR build + g1 scale (R23-proven).
__global__ __launch_bounds__(256) void k_build(
        const unsigned int* __restrict__ packed, const int* __restrict__ total,
        int* __restrict__ rowptr, float* __restrict__ dinv,
        unsigned short* __restrict__ esrc, __half* __restrict__ g1) {
    __shared__ int wsum[4];
    __shared__ int degl[256];
    __shared__ int curl[256];
    __shared__ float dinvl[256];
    __shared__ int bs2[2];
    const int b = blockIdx.x, t = threadIdx.x;
    const int lane = t & 63, w = t >> 6;
    {
        int v = (t < NBINS) ? total[t] : 0;
        int inc = v;
#pragma unroll
        for (int o = 1; o < 64; o <<= 1) {
            int u = __shfl_up(inc, o);
            if (lane >= o) inc += u;
        }
        if (lane == 63) wsum[w] = inc;
        __syncthreads();
        int off = 0;
        for (int k = 0; k < w; ++k) off += wsum[k];
        int excl = off + inc - v;
        if (t == b) bs2[0] = excl;
        if (t == b + 1) bs2[1] = excl;
        degl[t] = 0;
    }
    __syncthreads();
    const int s0 = bs2[0], s1 = bs2[1];
    for (int e = s0 + t; e < s1; e += 256)
        atomicAdd(&degl[(packed[e] >> 16) & 255], 1);
    __syncthreads();
    int dv = degl[t];
    {
        int inc = dv;
#pragma unroll
        for (int o = 1; o < 64; o <<= 1) {
            int u = __shfl_up(inc, o);
            if (lane >= o) inc += u;
        }
        if (lane == 63) wsum[w] = inc;
        __syncthreads();
        int off = 0;
        for (int k = 0; k < w; ++k) off += wsum[k];
        int excl = off + inc - dv;
        int node = b * 256 + t;
        float di = rsqrtf((float)dv + 1.0f);
        if (node < N_NODES) {
            rowptr[node] = s0 + excl;
            dinv[node] = di;
        }
        if (node == N_NODES) rowptr[N_NODES] = N_EDGES;
        dinvl[t] = di;
        curl[t] = excl;
    }
    __syncthreads();
    for (int e = s0 + t; e < s1; e += 256) {
        unsigned pk = packed[e];
        int ln = (pk >> 16) & 255;
        int pos = s0 + atomicAdd(&curl[ln], 1);
        esrc[pos] = (unsigned short)(pk & 0xFFFFu);
    }
    for (int idx = t; idx < 256 * 8; idx += 256) {
        int ln = idx >> 3;
        int node = b * 256 + ln;
        if (node < N_NODES) {
            float di = dinvl[ln];
            uint4 v4 = *(uint4*)&g1[(size_t)node * HID_DIM + (idx & 7) * 8];
            union { __half2 h2v[4]; uint4 u; } pk2;
            const __half2* hv = (const __half2*)&v4;
#pragma unroll
            for (int i = 0; i < 4; ++i) {
                float2 f = __half22float2(hv[i]);
                pk2.h2v[i] = __floats2half2_rn(f.x * di, f.y * di);
            }
            *(uint4*)&g1[(size_t)node * HID_DIM + (idx & 7) * 8] = pk2.u;
        }
    }
}

// K4: gather aggregation DIM=64, TWO NODES PER WAVE (one per 32-lane half).
// Per half: 4 parities x 8 channel lanes x 16B. Loop bounds use dmax =
// max(deg across halves) -> all __shfl at wave-uniform points (R9 lesson);
// gathers predicated by the half's own nb. Butterfly xor 8,16 only.
__global__ __launch_bounds__(256) void k_agg_relu(const int* __restrict__ rowptr,
        const unsigned short* __restrict__ esrc, const float* __restrict__ dinv,
        const uint4* __restrict__ g,        // [N][8] uint4 (=64 half)
        const float* __restrict__ b,
        __half* __restrict__ out) {         // agg1 [N][64] fp16
    int wid2 = (int)((blockIdx.x * (size_t)blockDim.x + threadIdx.x) >> 6);
    int lane = threadIdx.x & 63;
    if (wid2 >= N_NODES / 2) return;
    const int half = lane >> 5;
    const int hl = lane & 31;
    const int node = wid2 * 2 + half;
    const int p = hl >> 3;    // parity 0..3 within half
    const int c = lane & 7;   // uint4 channel group
    const int sb = half << 5; // shuffle source base of this half
    float a0 = 0.f, a1 = 0.f, a2 = 0.f, a3 = 0.f;
    float a4 = 0.f, a5 = 0.f, a6 = 0.f, a7 = 0.f;
#define ACC_U4(v)  do {                                            \
        float2 f0 = __half22float2(*(const __half2*)&(v).x);       \
        float2 f1 = __half22float2(*(const __half2*)&(v).y);       \
        float2 f2 = __half22float2(*(const __half2*)&(v).z);       \
        float2 f3 = __half22float2(*(const __half2*)&(v).w);       \
        a0 += f0.x; a1 += f0.y; a2 += f1.x; a3 += f1.y;            \
        a4 += f2.x; a5 += f2.y; a6 += f3.x; a7 += f3.y; } while (0)
    if (p == 0) { uint4 v = g[(size_t)node * 8 + c]; ACC_U4(v); }  // self-loop
    int beg = rowptr[node], deg = rowptr[node + 1] - beg;
    int dmax = max(deg, __shfl_xor(deg, 32));             // wave-uniform
    for (int base = 0; base < dmax; base += 32) {
        int nb = deg - base;                              // per-half (may be <=0)
        if (nb > 32) nb = 32;
        int ebmax = dmax - base; if (ebmax > 32) ebmax = 32;   // uniform
        int idx = (hl < nb) ? (int)esrc[beg + base + hl] : 0;
        for (int eb = 0; eb < ebmax; eb += 16) {          // uniform bound
            int e0 = eb + p;                              // e0+12 <= 31
            int s0 = __shfl(idx, sb + e0);
            int s1 = __shfl(idx, sb + e0 + 4);
            int s2 = __shfl(idx, sb + e0 + 8);
            int s3 = __shfl(idx, sb + e0 + 12);
            if (e0 + 12 < nb) {                           // fast path
                uint4 v0 = g[(size_t)s0 * 8 + c];
                uint4 v1 = g[(size_t)s1 * 8 + c];
                uint4 v2 = g[(size_t)s2 * 8 + c];
                uint4 v3 = g[(size_t)s3 * 8 + c];
                ACC_U4(v0); ACC_U4(v1); ACC_U4(v2); ACC_U4(v3);
            } else {                                      // tail: per-edge guard
                if (e0      < nb) { uint4 v = g[(size_t)s0 * 8 + c]; ACC_U4(v); }
                if (e0 + 4  < nb) { uint4 v = g[(size_t)s1 * 8 + c]; ACC_U4(v); }
                if (e0 + 8  < nb) { uint4 v = g[(size_t)s2 * 8 + c]; ACC_U4(v); }
            }
        }
    }
#undef ACC_U4
    a0 += __shfl_xor(a0, 8); a0 += __shfl_xor(a0, 16);
    a1 += __shfl_xor(a1, 8); a1 += __shfl_xor(a1, 16);
    a2 += __shfl_xor(a2, 8); a2 += __shfl_xor(a2, 16);
    a3 += __shfl_xor(a3, 8); a3 += __shfl_xor(a3, 16);
    a4 += __shfl_xor(a4, 8); a4 += __shfl_xor(a4, 16);
    a5 += __shfl_xor(a5, 8); a5 += __shfl_xor(a5, 16);
    a6 += __shfl_xor(a6, 8); a6 += __shfl_xor(a6, 16);
    a7 += __shfl_xor(a7, 8); a7 += __shfl_xor(a7, 16);
    if (hl < 8) {
        float dd = dinv[node];
        float4 b0v = *(const float4*)&b[c * 8 + 0];
        float4 b1v = *(const float4*)&b[c * 8 + 4];
        union { __half2 h2v[4]; uint4 u; } pk;
        pk.h2v[0] = __floats2half2_rn(fmaxf(a0 * dd + b0v.x, 0.f),
                                      fmaxf(a1 * dd + b0v.y, 0.f));
        pk.h2v[1] = __floats2half2_rn(fmaxf(a2 * dd + b0v.z, 0.f),
                                      fmaxf(a3 * dd + b0v.w, 0.f));
        pk.h2v[2] = __floats2half2_rn(fmaxf(a4 * dd + b1v.x, 0.f),
                                      fmaxf(a5 * dd + b1v.y, 0.f));
        pk.h2v[3] = __floats2half2_rn(fmaxf(a6 * dd + b1v.z, 0.f),
                                      fmaxf(a7 * dd + b1v.w, 0.f));
        *(uint4*)&out[(size_t)node * HID_DIM + c * 8] = pk.u;
    }
}

// K5: g2 = dinv * (a @ W2)  [50000,64]x[64,40]; fp16 in, fp16 out [N][40]
__global__ void k_gemm2(const __half* __restrict__ a, const float* __restrict__ W2,
                        const float* __restrict__ dinv, __half* __restrict__ g2) {
    int idx = blockIdx.x * blockDim.x + threadIdx.x;
    if (idx >= N_NODES * (OUT_DIM / 4)) return;
    int row = idx / (OUT_DIM / 4);
    int cg  = idx - row * (OUT_DIM / 4);
    const uint2* ar = (const uint2*)(a + (size_t)row * HID_DIM);
    float4 acc = make_float4(0.f, 0.f, 0.f, 0.f);
#pragma unroll
    for (int kk = 0; kk < 16; ++kk) {
        uint2 hv = ar[kk];
        float2 f0 = __half22float2(*(const __half2*)&hv.x);
        float2 f1 = __half22float2(*(const __half2*)&hv.y);
        float4 w0 = *(const float4*)&W2[(kk * 4 + 0) * OUT_DIM + cg * 4];
        float4 w1 = *(const float4*)&W2[(kk * 4 + 1) * OUT_DIM + cg * 4];
        float4 w2 = *(const float4*)&W2[(kk * 4 + 2) * OUT_DIM + cg * 4];
        float4 w3 = *(const float4*)&W2[(kk * 4 + 3) * OUT_DIM + cg * 4];
        acc.x += f0.x * w0.x + f0.y * w1.x + f1.x * w2.x + f1.y * w3.x;
        acc.y += f0.x * w0.y + f0.y * w1.y + f1.x * w2.y + f1.y * w3.y;
        acc.z += f0.x * w0.z + f0.y * w1.z + f1.x * w2.z + f1.y * w3.z;
        acc.w += f0.x * w0.w + f0.y * w1.w + f1.x * w2.w + f1.y * w3.w;
    }
    float dv = dinv[row];
    union { __half2 h2v[2]; uint2 u; } pk;
    pk.h2v[0] = __floats2half2_rn(acc.x * dv, acc.y * dv);
    pk.h2v[1] = __floats2half2_rn(acc.z * dv, acc.w * dv);
    *(uint2*)&g2[(size_t)row * OUT_DIM + cg * 4] = pk.u;
}

// K6: layer-2 aggregation, TWO NODES PER WAVE. Per half: 2 parities x 16
// channel lanes (act c<10). Same uniform-shuffle discipline as K4.
__global__ __launch_bounds__(256) void k_agg_lsm(const int* __restrict__ rowptr,
        const unsigned short* __restrict__ esrc, const float* __restrict__ dinv,
        const uint2* __restrict__ g,        // [N][10] uint2 (=40 half)
        const float* __restrict__ b,
        float* __restrict__ out) {
    int wid2 = (int)((blockIdx.x * (size_t)blockDim.x + threadIdx.x) >> 6);
    int lane = threadIdx.x & 63;
    if (wid2 >= N_NODES / 2) return;
    const int half = lane >> 5;
    const int hl = lane & 31;
    const int node = wid2 * 2 + half;
    const int p = hl >> 4;    // parity 0..1 within half
    const int c = hl & 15;
    const int sb = half << 5;
    bool act = (c < 10);
    float ax = 0.f, ay = 0.f, az = 0.f, aw = 0.f;
#define ACC_U2(v)  do {                                            \
        float2 f0 = __half22float2(*(const __half2*)&(v).x);       \
        float2 f1 = __half22float2(*(const __half2*)&(v).y);       \
        ax += f0.x; ay += f0.y; az += f1.x; aw += f1.y; } while (0)
    if (p == 0 && act) { uint2 v = g[(size_t)node * 10 + c]; ACC_U2(v); }
    int beg = rowptr[node], deg = rowptr[node + 1] - beg;
    int dmax = max(deg, __shfl_xor(deg, 32));             // wave-uniform
    for (int base = 0; base < dmax; base += 32) {
        int nb = deg - base; if (nb > 32) nb = 32;        // per-half
        int ebmax = dmax - base; if (ebmax > 32) ebmax = 32;   // uniform
        int idx = (hl < nb) ? (int)esrc[beg + base + hl] : 0;
        for (int eb = 0; eb < ebmax; eb += 8) {           // uniform bound
            int e0 = eb + p;                              // e0+6 <= 31
            int s0 = __shfl(idx, sb + e0);
            int s1 = __shfl(idx, sb + e0 + 2);
            int s2 = __shfl(idx, sb + e0 + 4);
            int s3 = __shfl(idx, sb + e0 + 6);
            if (act) {
                if (e0 + 6 < nb) {
                    uint2 v0 = g[(size_t)s0 * 10 + c];
                    uint2 v1 = g[(size_t)s1 * 10 + c];
                    uint2 v2 = g[(size_t)s2 * 10 + c];
                    uint2 v3 = g[(size_t)s3 * 10 + c];
                    ACC_U2(v0); ACC_U2(v1); ACC_U2(v2); ACC_U2(v3);
                } else {
                    if (e0      < nb) { uint2 v = g[(size_t)s0 * 10 + c]; ACC_U2(v); }
                    if (e0 + 2  < nb) { uint2 v = g[(size_t)s1 * 10 + c]; ACC_U2(v); }
                    if (e0 + 4  < nb) { uint2 v = g[(size_t)s2 * 10 + c]; ACC_U2(v); }
                }
            }
        }
    }
#undef ACC_U2
    ax += __shfl_xor(ax, 16);
    ay += __shfl_xor(ay, 16);
    az += __shfl_xor(az, 16);
    aw += __shfl_xor(aw, 16);
    float dd = dinv[node];
    float vx = -INFINITY, vy = -INFINITY, vz = -INFINITY, vw = -INFINITY;
    if (act) {
        float4 bb = *(const float4*)&b[c * 4];
        vx = ax * dd + bb.x; vy = ay * dd + bb.y;
        vz = az * dd + bb.z; vw = aw * dd + bb.w;
    }
    float m = fmaxf(fmaxf(vx, vy), fmaxf(vz, vw));
    for (int o = 8; o; o >>= 1) m = fmaxf(m, __shfl_xor(m, o));   // within 16
    float es = act ? (__expf(vx - m) + __expf(vy - m) + __expf(vz - m) + __expf(vw - m)) : 0.f;
    for (int o = 8; o; o >>= 1) es += __shfl_xor(es, o);
    float ls = __logf(es);
    if (hl < 16 && act) {
        float4 o4 = make_float4(vx - m - ls, vy - m - ls, vz - m - ls, vw - m - ls);
        *(float4*)&out[(size_t)node * OUT_DIM + c * 4] = o4;
    }
}

extern "C" void kernel_launch(void* const* d_in, const int* in_sizes, int n_in,
                              void* d_out, int out_size, void* d_ws, size_t ws_size,
                              hipStream_t stream) {
    const float* x    = (const float*)d_in[0];
    const int*   ei   = (const int*)d_in[1];
    const int*   srcp = ei;             // edge_index[0]
    const int*   dstp = ei + N_EDGES;   // edge_index[1]
    const float* W1   = (const float*)d_in[2];
    const float* b1   = (const float*)d_in[3];
    const float* W2   = (const float*)d_in[4];
    const float* b2   = (const float*)d_in[5];
    float* out = (float*)d_out;

    // workspace layout (~25 MB)
    char* p = (char*)d_ws;
    int*            hist   = (int*)p;            p += (size_t)EH_BLOCKS * NBINS * 4;
    int*            total  = (int*)p;            p += 256 * 4;
    int*            rowptr = (int*)p;            p += (size_t)(N_NODES + 4) * 4;
    unsigned int*   packed = (unsigned int*)p;   p += (size_t)N_EDGES * 4;
    unsigned short* esrc   = (unsigned short*)p; p += (size_t)N_EDGES * 2;
    float*          dinv   = (float*)p;          p += (size_t)N_NODES * 4;
    __half*         w1t    = (__half*)p;         p += (size_t)IN_DIM * HID_DIM * 2;
    __half*         g1     = (__half*)p;         p += (size_t)N_NODES * HID_DIM * 2;
    __half*         agg1   = (__half*)p;         p += (size_t)N_NODES * HID_DIM * 2;
    __half*         g2     = (__half*)p;         p += (size_t)N_NODES * OUT_DIM * 2;

    k_init_hist<<<INIT_BLOCKS + EH_BLOCKS, 256, 0, stream>>>(W1, w1t, dstp, hist);

    k_gemm1_scan<<<GEMM1_BLOCKS + NBINS, 256, 0, stream>>>(x, w1t, g1, hist, total);

    k_scatter1<<<EH_BLOCKS, 256, 0, stream>>>(srcp, dstp, hist, total, packed);

    k_build<<<NBINS, 256, 0, stream>>>(packed, total, rowptr, dinv, esrc, g1);

    k_agg_relu<<<(N_NODES / 2 + 3) / 4, 256, 0, stream>>>(rowptr, esrc, dinv,
                                                          (const uint4*)g1, b1, agg1);

    k_gemm2<<<(N_NODES * (OUT_DIM / 4) + 255) / 256, 256, 0, stream>>>(agg1, W2, dinv, g2);

    k_agg_lsm<<<(N_NODES / 2 + 3) / 4, 256, 0, stream>>>(rowptr, esrc, dinv,
                                                         (const uint2*)g2, b2, out);
}

// Round 26
// 118.185 us; speedup vs baseline: 1.1777x; 1.0018x over previous
//
#include <hip/hip_runtime.h>
#include <hip/hip_bf16.h>
#include <hip/hip_fp16.h>
#include <cstddef>

#define N_NODES 50000
#define IN_DIM 256
#define HID_DIM 64
#define OUT_DIM 40
#define N_EDGES 800000
#define NBINS 196           // ceil(N_NODES / 256); bin(d) = d >> 8
#define GEMM1_BLOCKS 782    // ceil(N_NODES / 64)
#define EH_BLOCKS 3125      // ceil(N_EDGES / 256)
#define INIT_BLOCKS 64      // w1t conversion

typedef _Float16 f16x8 __attribute__((ext_vector_type(8)));
typedef float f32x4 __attribute__((ext_vector_type(4)));

// ---------------------------------------------------------------------------
// K0: FUSED w1t build + coarse histogram (dst>>8), LDS atomics only.
__global__ __launch_bounds__(256) void k_init_hist(
        const float* __restrict__ W1, __half* __restrict__ w1t,
        const int* __restrict__ dst, int* __restrict__ hist) {
    __shared__ int lh[NBINS];
    const int tid = threadIdx.x;
    if (blockIdx.x >= INIT_BLOCKS) {             // ---- hist path ----
        if (tid < NBINS) lh[tid] = 0;
        __syncthreads();
        int i = (blockIdx.x - INIT_BLOCKS) * 256 + tid;
        if (i < N_EDGES) atomicAdd(&lh[dst[i] >> 8], 1);   // LDS atomic
        __syncthreads();
        if (tid < NBINS)
            hist[(size_t)(blockIdx.x - INIT_BLOCKS) * NBINS + tid] = lh[tid];
        return;
    }
    int i = blockIdx.x * 256 + tid;
    if (i < IN_DIM * HID_DIM) {
        int c = i >> 8, k = i & 255;
        w1t[i] = __float2half(W1[(size_t)k * HID_DIM + c]);
    }
}

// K1: FUSED gemm1 (UNSCALED g1) + per-bin column scan of hist.
__global__ __launch_bounds__(256) void k_gemm1_scan(
        const float* __restrict__ x, const __half* __restrict__ w1t,
        __half* __restrict__ g1,
        int* __restrict__ hist, int* __restrict__ total) {
    __shared__ _Float16 xh[64][72];   // 18 KB; scan path uses first 16 B
    __shared__ _Float16 wt[64][72];
    const int tid = threadIdx.x;
    if (blockIdx.x >= GEMM1_BLOCKS) {            // ---- scanbins path ----
        int* wsum = (int*)&xh[0][0];             // 4 ints
        const int b = blockIdx.x - GEMM1_BLOCKS;
        const int lane = tid & 63, w = tid >> 6;
        int vals[13];
        int lsum = 0;
#pragma unroll
        for (int i = 0; i < 13; ++i) {
            int j = tid * 13 + i;
            vals[i] = (j < EH_BLOCKS) ? hist[(size_t)j * NBINS + b] : 0;
            lsum += vals[i];
        }
        int inc = lsum;
#pragma unroll
        for (int o = 1; o < 64; o <<= 1) {
            int u = __shfl_up(inc, o);
            if (lane >= o) inc += u;
        }
        if (lane == 63) wsum[w] = inc;
        __syncthreads();
        int off = 0;
        for (int k = 0; k < w; ++k) off += wsum[k];
        int run = off + inc - lsum;
#pragma unroll
        for (int i = 0; i < 13; ++i) {
            int j = tid * 13 + i;
            if (j < EH_BLOCKS) hist[(size_t)j * NBINS + b] = run;
            run += vals[i];
        }
        if (tid == 255) total[b] = run;
        return;
    }
    // ---- gemm1 path (four K=64 phases, 18 KB LDS) ----
    const int row0 = blockIdx.x * 64;
    const int r = tid >> 2, q = tid & 3;
    const int wv = tid >> 6, l = tid & 63;
    const int rowa = wv * 16 + (l & 15);
    const int koff = (l >> 4) * 8;
    const int grow_s = row0 + r;
    f32x4 acc0 = {0.f, 0.f, 0.f, 0.f}, acc1 = acc0, acc2 = acc0, acc3 = acc0;
#pragma unroll
    for (int kh = 0; kh < 4; ++kh) {
        __syncthreads();
        {
            const uint4* wsrc = (const uint4*)(w1t + (size_t)r * 256 + kh * 64 + q * 16);
            uint4* wdst = (uint4*)&wt[r][q * 16];
            wdst[0] = wsrc[0];
            wdst[1] = wsrc[1];
            const float4* xsrc = (const float4*)(x + (size_t)grow_s * IN_DIM + kh * 64 + q * 16);
#pragma unroll
            for (int i = 0; i < 2; ++i) {
                float4 f0 = make_float4(0.f, 0.f, 0.f, 0.f), f1 = f0;
                if (grow_s < N_NODES) { f0 = xsrc[2 * i]; f1 = xsrc[2 * i + 1]; }
                f16x8 v;
                v[0] = (_Float16)f0.x; v[1] = (_Float16)f0.y;
                v[2] = (_Float16)f0.z; v[3] = (_Float16)f0.w;
                v[4] = (_Float16)f1.x; v[5] = (_Float16)f1.y;
                v[6] = (_Float16)f1.z; v[7] = (_Float16)f1.w;
                *(f16x8*)&xh[r][q * 16 + i * 8] = v;
            }
        }
        __syncthreads();
#pragma unroll
        for (int ks = 0; ks < 2; ++ks) {
            f16x8 a  = *(const f16x8*)&xh[rowa][ks * 32 + koff];
            f16x8 b0 = *(const f16x8*)&wt[ 0 + (l & 15)][ks * 32 + koff];
            f16x8 b1 = *(const f16x8*)&wt[16 + (l & 15)][ks * 32 + koff];
            f16x8 b2 = *(const f16x8*)&wt[32 + (l & 15)][ks * 32 + koff];
            f16x8 b3 = *(const f16x8*)&wt[48 + (l & 15)][ks * 32 + koff];
            acc0 = __builtin_amdgcn_mfma_f32_16x16x32_f16(a, b0, acc0, 0, 0, 0);
            acc1 = __builtin_amdgcn_mfma_f32_16x16x32_f16(a, b1, acc1, 0, 0, 0);
            acc2 = __builtin_amdgcn_mfma_f32_16x16x32_f16(a, b2, acc2, 0, 0, 0);
            acc3 = __builtin_amdgcn_mfma_f32_16x16x32_f16(a, b3, acc3, 0, 0, 0);
        }
    }
    // C/D: col = lane&15, row = (lane>>4)*4 + reg  [m89-verified]
    const int colc = l & 15;
#pragma unroll
    for (int rr = 0; rr < 4; ++rr) {
        int grow = row0 + wv * 16 + (l >> 4) * 4 + rr;
        if (grow < N_NODES) {
            __half* dst2 = g1 + (size_t)grow * HID_DIM;
            dst2[ 0 + colc] = __float2half(acc0[rr]);
            dst2[16 + colc] = __float2half(acc1[rr]);
            dst2[32 + colc] = __float2half(acc2[rr]);
            dst2[48 + colc] = __float2half(acc3[rr]);
        }
    }
}

// K2: scatter edges into bucket-grouped packed array (LDS atomics only).
__global__ __launch_bounds__(256) void k_scatter1(
        const int* __restrict__ src, const int* __restrict__ dst,
        const int* __restrict__ hist, const int* __restrict__ total,
        unsigned int* __restrict__ packed) {
    __shared__ int wsum[4];
    __shared__ int cursor[NBINS];
    const int t = threadIdx.x;
    const int lane = t & 63, w = t >> 6;
    int v = (t < NBINS) ? total[t] : 0;
    int inc = v;
#pragma unroll
    for (int o = 1; o < 64; o <<= 1) {
        int u = __shfl_up(inc, o);
        if (lane >= o) inc += u;
    }
    if (lane == 63) wsum[w] = inc;
    __syncthreads();
    int off = 0;
    for (int k = 0; k < w; ++k) off += wsum[k];
    int excl = off + inc - v;
    if (t < NBINS)
        cursor[t] = excl + hist[(size_t)blockIdx.x * NBINS + t];
    __syncthreads();
    int i = blockIdx.x * 256 + t;
    if (i < N_EDGES) {
        int d = dst[i], s = src[i];
        int pos = atomicAdd(&cursor[d >> 8], 1);          // LDS atomic
        packed[pos] = ((unsigned)d << 16) | (unsigned)s;
    }
}

// K3: per-bin CSR build + g1 scale (R23-proven).
__global__ __launch_bounds__(256) void k_build(
        const unsigned int* __restrict__ packed, const int* __restrict__ total,
        int* __restrict__ rowptr, float* __restrict__ dinv,
        unsigned short* __restrict__ esrc, __half* __restrict__ g1) {
    __shared__ int wsum[4];
    __shared__ int degl[256];
    __shared__ int curl[256];
    __shared__ float dinvl[256];
    __shared__ int bs2[2];
    const int b = blockIdx.x, t = threadIdx.x;
    const int lane = t & 63, w = t >> 6;
    {
        int v = (t < NBINS) ? total[t] : 0;
        int inc = v;
#pragma unroll
        for (int o = 1; o < 64; o <<= 1) {
            int u = __shfl_up(inc, o);
            if (lane >= o) inc += u;
        }
        if (lane == 63) wsum[w] = inc;
        __syncthreads();
        int off = 0;
        for (int k = 0; k < w; ++k) off += wsum[k];
        int excl = off + inc - v;
        if (t == b) bs2[0] = excl;
        if (t == b + 1) bs2[1] = excl;
        degl[t] = 0;
    }
    __syncthreads();
    const int s0 = bs2[0], s1 = bs2[1];
    for (int e = s0 + t; e < s1; e += 256)
        atomicAdd(&degl[(packed[e] >> 16) & 255], 1);
    __syncthreads();
    int dv = degl[t];
    {
        int inc = dv;
#pragma unroll
        for (int o = 1; o < 64; o <<= 1) {
            int u = __shfl_up(inc, o);
            if (lane >= o) inc += u;
        }
        if (lane == 63) wsum[w] = inc;
        __syncthreads();
        int off = 0;
        for (int k = 0; k < w; ++k) off += wsum[k];
        int excl = off + inc - dv;
        int node = b * 256 + t;
        float di = rsqrtf((float)dv + 1.0f);
        if (node < N_NODES) {
            rowptr[node] = s0 + excl;
            dinv[node] = di;
        }
        if (node == N_NODES) rowptr[N_NODES] = N_EDGES;
        dinvl[t] = di;
        curl[t] = excl;
    }
    __syncthreads();
    for (int e = s0 + t; e < s1; e += 256) {
        unsigned pk = packed[e];
        int ln = (pk >> 16) & 255;
        int pos = s0 + atomicAdd(&curl[ln], 1);
        esrc[pos] = (unsigned short)(pk & 0xFFFFu);
    }
    for (int idx = t; idx < 256 * 8; idx += 256) {
        int ln = idx >> 3;
        int node = b * 256 + ln;
        if (node < N_NODES) {
            float di = dinvl[ln];
            uint4 v4 = *(uint4*)&g1[(size_t)node * HID_DIM + (idx & 7) * 8];
            union { __half2 h2v[4]; uint4 u; } pk2;
            const __half2* hv = (const __half2*)&v4;
#pragma unroll
            for (int i = 0; i < 4; ++i) {
                float2 f = __half22float2(hv[i]);
                pk2.h2v[i] = __floats2half2_rn(f.x * di, f.y * di);
            }
            *(uint4*)&g1[(size_t)node * HID_DIM + (idx & 7) * 8] = pk2.u;
        }
    }
}

// K4: gather aggregation DIM=64, FOUR NODES PER WAVE (16 lanes per node:
// 2 parities x 8 uint4-channels). dmax = max deg over the 4 quarters via
// two xor-shuffles -> all loop bounds wave-uniform; shuffles unconditional;
// gathers predicated by the quarter's own nb (R9 discipline). Butterfly xor-8.
__global__ __launch_bounds__(256) void k_agg_relu(const int* __restrict__ rowptr,
        const unsigned short* __restrict__ esrc, const float* __restrict__ dinv,
        const uint4* __restrict__ g,        // [N][8] uint4 (=64 half)
        const float* __restrict__ b,
        __half* __restrict__ out) {         // agg1 [N][64] fp16
    int wid4 = (int)((blockIdx.x * (size_t)blockDim.x + threadIdx.x) >> 6);
    int lane = threadIdx.x & 63;
    if (wid4 >= N_NODES / 4) return;        // 50000 % 4 == 0
    const int q  = lane >> 4;               // quarter 0..3
    const int ql = lane & 15;               // lane within quarter
    const int node = wid4 * 4 + q;
    const int p = (lane >> 3) & 1;          // parity 0..1 within quarter
    const int c = lane & 7;                 // uint4 channel group
    const int sb = q << 4;                  // shuffle source base
    float a0 = 0.f, a1 = 0.f, a2 = 0.f, a3 = 0.f;
    float a4 = 0.f, a5 = 0.f, a6 = 0.f, a7 = 0.f;
#define ACC_U4(v)  do {                                            \
        float2 f0 = __half22float2(*(const __half2*)&(v).x);       \
        float2 f1 = __half22float2(*(const __half2*)&(v).y);       \
        float2 f2 = __half22float2(*(const __half2*)&(v).z);       \
        float2 f3 = __half22float2(*(const __half2*)&(v).w);       \
        a0 += f0.x; a1 += f0.y; a2 += f1.x; a3 += f1.y;            \
        a4 += f2.x; a5 += f2.y; a6 += f3.x; a7 += f3.y; } while (0)
    if (p == 0) { uint4 v = g[(size_t)node * 8 + c]; ACC_U4(v); }  // self-loop
    int beg = rowptr[node], deg = rowptr[node + 1] - beg;
    int dmax = max(deg, __shfl_xor(deg, 16));
    dmax = max(dmax, __shfl_xor(dmax, 32));             // uniform across wave
    for (int base = 0; base < dmax; base += 16) {
        int nb = deg - base; if (nb > 16) nb = 16;      // per-quarter
        int ebmax = dmax - base; if (ebmax > 16) ebmax = 16;   // uniform
        int idx = (ql < nb) ? (int)esrc[beg + base + ql] : 0;
        for (int eb = 0; eb < ebmax; eb += 8) {         // uniform bound
            int e0 = eb + p;                            // e0+6 <= 15
            int s0 = __shfl(idx, sb + e0);
            int s1 = __shfl(idx, sb + e0 + 2);
            int s2 = __shfl(idx, sb + e0 + 4);
            int s3 = __shfl(idx, sb + e0 + 6);
            if (e0 + 6 < nb) {                          // fast path
                uint4 v0 = g[(size_t)s0 * 8 + c];
                uint4 v1 = g[(size_t)s1 * 8 + c];
                uint4 v2 = g[(size_t)s2 * 8 + c];
                uint4 v3 = g[(size_t)s3 * 8 + c];
                ACC_U4(v0); ACC_U4(v1); ACC_U4(v2); ACC_U4(v3);
            } else {                                    // tail: per-edge guard
                if (e0      < nb) { uint4 v = g[(size_t)s0 * 8 + c]; ACC_U4(v); }
                if (e0 + 2  < nb) { uint4 v = g[(size_t)s1 * 8 + c]; ACC_U4(v); }
                if (e0 + 4  < nb) { uint4 v = g[(size_t)s2 * 8 + c]; ACC_U4(v); }
            }
        }
    }
#undef ACC_U4
    a0 += __shfl_xor(a0, 8);
    a1 += __shfl_xor(a1, 8);
    a2 += __shfl_xor(a2, 8);
    a3 += __shfl_xor(a3, 8);
    a4 += __shfl_xor(a4, 8);
    a5 += __shfl_xor(a5, 8);
    a6 += __shfl_xor(a6, 8);
    a7 += __shfl_xor(a7, 8);
    if (ql < 8) {
        float dd = dinv[node];
        float4 b0v = *(const float4*)&b[c * 8 + 0];
        float4 b1v = *(const float4*)&b[c * 8 + 4];
        union { __half2 h2v[4]; uint4 u; } pk;
        pk.h2v[0] = __floats2half2_rn(fmaxf(a0 * dd + b0v.x, 0.f),
                                      fmaxf(a1 * dd + b0v.y, 0.f));
        pk.h2v[1] = __floats2half2_rn(fmaxf(a2 * dd + b0v.z, 0.f),
                                      fmaxf(a3 * dd + b0v.w, 0.f));
        pk.h2v[2] = __floats2half2_rn(fmaxf(a4 * dd + b1v.x, 0.f),
                                      fmaxf(a5 * dd + b1v.y, 0.f));
        pk.h2v[3] = __floats2half2_rn(fmaxf(a6 * dd + b1v.z, 0.f),
                                      fmaxf(a7 * dd + b1v.w, 0.f));
        *(uint4*)&out[(size_t)node * HID_DIM + c * 8] = pk.u;
    }
}

// K5: g2 = dinv * (a @ W2)  [50000,64]x[64,40]; fp16 in, fp16 out [N][40]
__global__ void k_gemm2(const __half* __restrict__ a, const float* __restrict__ W2,
                        const float* __restrict__ dinv, __half* __restrict__ g2) {
    int idx = blockIdx.x * blockDim.x + threadIdx.x;
    if (idx >= N_NODES * (OUT_DIM / 4)) return;
    int row = idx / (OUT_DIM / 4);
    int cg  = idx - row * (OUT_DIM / 4);
    const uint2* ar = (const uint2*)(a + (size_t)row * HID_DIM);
    float4 acc = make_float4(0.f, 0.f, 0.f, 0.f);
#pragma unroll
    for (int kk = 0; kk < 16; ++kk) {
        uint2 hv = ar[kk];
        float2 f0 = __half22float2(*(const __half2*)&hv.x);
        float2 f1 = __half22float2(*(const __half2*)&hv.y);
        float4 w0 = *(const float4*)&W2[(kk * 4 + 0) * OUT_DIM + cg * 4];
        float4 w1 = *(const float4*)&W2[(kk * 4 + 1) * OUT_DIM + cg * 4];
        float4 w2 = *(const float4*)&W2[(kk * 4 + 2) * OUT_DIM + cg * 4];
        float4 w3 = *(const float4*)&W2[(kk * 4 + 3) * OUT_DIM + cg * 4];
        acc.x += f0.x * w0.x + f0.y * w1.x + f1.x * w2.x + f1.y * w3.x;
        acc.y += f0.x * w0.y + f0.y * w1.y + f1.x * w2.y + f1.y * w3.y;
        acc.z += f0.x * w0.z + f0.y * w1.z + f1.x * w2.z + f1.y * w3.z;
        acc.w += f0.x * w0.w + f0.y * w1.w + f1.x * w2.w + f1.y * w3.w;
    }
    float dv = dinv[row];
    union { __half2 h2v[2]; uint2 u; } pk;
    pk.h2v[0] = __floats2half2_rn(acc.x * dv, acc.y * dv);
    pk.h2v[1] = __floats2half2_rn(acc.z * dv, acc.w * dv);
    *(uint2*)&g2[(size_t)row * OUT_DIM + cg * 4] = pk.u;
}

// K6: layer-2 aggregation, TWO NODES PER WAVE (R25-proven).
__global__ __launch_bounds__(256) void k_agg_lsm(const int* __restrict__ rowptr,
        const unsigned short* __restrict__ esrc, const float* __restrict__ dinv,
        const uint2* __restrict__ g,        // [N][10] uint2 (=40 half)
        const float* __restrict__ b,
        float* __restrict__ out) {
    int wid2 = (int)((blockIdx.x * (size_t)blockDim.x + threadIdx.x) >> 6);
    int lane = threadIdx.x & 63;
    if (wid2 >= N_NODES / 2) return;
    const int half = lane >> 5;
    const int hl = lane & 31;
    const int node = wid2 * 2 + half;
    const int p = hl >> 4;    // parity 0..1 within half
    const int c = hl & 15;
    const int sb = half << 5;
    bool act = (c < 10);
    float ax = 0.f, ay = 0.f, az = 0.f, aw = 0.f;
#define ACC_U2(v)  do {                                            \
        float2 f0 = __half22float2(*(const __half2*)&(v).x);       \
        float2 f1 = __half22float2(*(const __half2*)&(v).y);       \
        ax += f0.x; ay += f0.y; az += f1.x; aw += f1.y; } while (0)
    if (p == 0 && act) { uint2 v = g[(size_t)node * 10 + c]; ACC_U2(v); }
    int beg = rowptr[node], deg = rowptr[node + 1] - beg;
    int dmax = max(deg, __shfl_xor(deg, 32));             // wave-uniform
    for (int base = 0; base < dmax; base += 32) {
        int nb = deg - base; if (nb > 32) nb = 32;        // per-half
        int ebmax = dmax - base; if (ebmax > 32) ebmax = 32;   // uniform
        int idx = (hl < nb) ? (int)esrc[beg + base + hl] : 0;
        for (int eb = 0; eb < ebmax; eb += 8) {           // uniform bound
            int e0 = eb + p;                              // e0+6 <= 31
            int s0 = __shfl(idx, sb + e0);
            int s1 = __shfl(idx, sb + e0 + 2);
            int s2 = __shfl(idx, sb + e0 + 4);
            int s3 = __shfl(idx, sb + e0 + 6);
            if (act) {
                if (e0 + 6 < nb) {
                    uint2 v0 = g[(size_t)s0 * 10 + c];
                    uint2 v1 = g[(size_t)s1 * 10 + c];
                    uint2 v2 = g[(size_t)s2 * 10 + c];
                    uint2 v3 = g[(size_t)s3 * 10 + c];
                    ACC_U2(v0); ACC_U2(v1); ACC_U2(v2); ACC_U2(v3);
                } else {
                    if (e0      < nb) { uint2 v = g[(size_t)s0 * 10 + c]; ACC_U2(v); }
                    if (e0 + 2  < nb) { uint2 v = g[(size_t)s1 * 10 + c]; ACC_U2(v); }
                    if (e0 + 4  < nb) { uint2 v = g[(size_t)s2 * 10 + c]; ACC_U2(v); }
                }
            }
        }
    }
#undef ACC_U2
    ax += __shfl_xor(ax, 16);
    ay += __shfl_xor(ay, 16);
    az += __shfl_xor(az, 16);
    aw += __shfl_xor(aw, 16);
    float dd = dinv[node];
    float vx = -INFINITY, vy = -INFINITY, vz = -INFINITY, vw = -INFINITY;
    if (act) {
        float4 bb = *(const float4*)&b[c * 4];
        vx = ax * dd + bb.x; vy = ay * dd + bb.y;
        vz = az * dd + bb.z; vw = aw * dd + bb.w;
    }
    float m = fmaxf(fmaxf(vx, vy), fmaxf(vz, vw));
    for (int o = 8; o; o >>= 1) m = fmaxf(m, __shfl_xor(m, o));   // within 16
    float es = act ? (__expf(vx - m) + __expf(vy - m) + __expf(vz - m) + __expf(vw - m)) : 0.f;
    for (int o = 8; o; o >>= 1) es += __shfl_xor(es, o);
    float ls = __logf(es);
    if (hl < 16 && act) {
        float4 o4 = make_float4(vx - m - ls, vy - m - ls, vz - m - ls, vw - m - ls);
        *(float4*)&out[(size_t)node * OUT_DIM + c * 4] = o4;
    }
}

extern "C" void kernel_launch(void* const* d_in, const int* in_sizes, int n_in,
                              void* d_out, int out_size, void* d_ws, size_t ws_size,
                              hipStream_t stream) {
    const float* x    = (const float*)d_in[0];
    const int*   ei   = (const int*)d_in[1];
    const int*   srcp = ei;             // edge_index[0]
    const int*   dstp = ei + N_EDGES;   // edge_index[1]
    const float* W1   = (const float*)d_in[2];
    const float* b1   = (const float*)d_in[3];
    const float* W2   = (const float*)d_in[4];
    const float* b2   = (const float*)d_in[5];
    float* out = (float*)d_out;

    // workspace layout (~25 MB)
    char* p = (char*)d_ws;
    int*            hist   = (int*)p;            p += (size_t)EH_BLOCKS * NBINS * 4;
    int*            total  = (int*)p;            p += 256 * 4;
    int*            rowptr = (int*)p;            p += (size_t)(N_NODES + 4) * 4;
    unsigned int*   packed = (unsigned int*)p;   p += (size_t)N_EDGES * 4;
    unsigned short* esrc   = (unsigned short*)p; p += (size_t)N_EDGES * 2;
    float*          dinv   = (float*)p;          p += (size_t)N_NODES * 4;
    __half*         w1t    = (__half*)p;         p += (size_t)IN_DIM * HID_DIM * 2;
    __half*         g1     = (__half*)p;         p += (size_t)N_NODES * HID_DIM * 2;
    __half*         agg1   = (__half*)p;         p += (size_t)N_NODES * HID_DIM * 2;
    __half*         g2     = (__half*)p;         p += (size_t)N_NODES * OUT_DIM * 2;

    k_init_hist<<<INIT_BLOCKS + EH_BLOCKS, 256, 0, stream>>>(W1, w1t, dstp, hist);

    k_gemm1_scan<<<GEMM1_BLOCKS + NBINS, 256, 0, stream>>>(x, w1t, g1, hist, total);

    k_scatter1<<<EH_BLOCKS, 256, 0, stream>>>(srcp, dstp, hist, total, packed);

    k_build<<<NBINS, 256, 0, stream>>>(packed, total, rowptr, dinv, esrc, g1);

    k_agg_relu<<<(N_NODES / 4 + 3) / 4, 256, 0, stream>>>(rowptr, esrc, dinv,
                                                          (const uint4*)g1, b1, agg1);

    k_gemm2<<<(N_NODES * (OUT_DIM / 4) + 255) / 256, 256, 0, stream>>>(agg1, W2, dinv, g2);

    k_agg_lsm<<<(N_NODES / 2 + 3) / 4, 256, 0, stream>>>(rowptr, esrc, dinv,
                                                         (const uint2*)g2, b2, out);
}